// Round 14
// baseline (218.282 us; speedup 1.0000x reference)
//
#include <hip/hip_runtime.h>

constexpr int B = 16, N = 128, D = 128, DN0 = 64, DE0 = 16;

typedef _Float16 half8 __attribute__((ext_vector_type(8)));
typedef _Float16 half4 __attribute__((ext_vector_type(4)));
typedef float floatx4 __attribute__((ext_vector_type(4)));
typedef float floatx16 __attribute__((ext_vector_type(16)));

// async 16B global->LDS. msg0/T2 global layout is cell-swizzled
// (16B cell g of row j stored at g^(j&15)) so linear copies land
// conflict-free in LDS.
__device__ __forceinline__ void gld16(const _Float16* g, _Float16* l) {
  __builtin_amdgcn_global_load_lds(
      (const __attribute__((address_space(1))) void*)g,
      (__attribute__((address_space(3))) void*)l, 16, 0, 0);
}

// ---------------------------------------------------------------------------
// K1: merged prep. R21 (kept): xi0/xj0 BATCHED 4 rows/block (512 blocks).
// bid >= 512 (128 blocks): WeT transposes. Weights k-major (R15).
// ---------------------------------------------------------------------------
__global__ __launch_bounds__(256) void k_pre(
    const float* __restrict__ x, const float* __restrict__ wm0,
    const float* __restrict__ bm0, const float* __restrict__ wm1,
    const float* __restrict__ wm2,
    float* __restrict__ xi0, float* __restrict__ xj0,
    _Float16* __restrict__ weT1, _Float16* __restrict__ weT2) {
  const int bid = blockIdx.x;
  const int t = threadIdx.x;
  if (bid < 512) {
    const int r0 = bid * 4;
    const int half = t >> 7, c = t & 127;
    __shared__ float sX[4][DN0];
    ((float*)sX)[t] = x[(size_t)r0 * DN0 + t];
    __syncthreads();
    float acc[4];
    #pragma unroll
    for (int r = 0; r < 4; ++r) acc[r] = half ? 0.f : bm0[c];
    const float* wb0 = wm0 + half * DN0 * D;
    #pragma unroll 4
    for (int k4 = 0; k4 < DN0; k4 += 4) {
      const float* wb = wb0 + k4 * D + c;
      const float w0 = wb[0], w1 = wb[D], w2 = wb[2 * D], w3 = wb[3 * D];
      #pragma unroll
      for (int r = 0; r < 4; ++r) {
        const float4 xv = *(const float4*)&sX[r][k4];
        acc[r] = fmaf(xv.x, w0, acc[r]);
        acc[r] = fmaf(xv.y, w1, acc[r]);
        acc[r] = fmaf(xv.z, w2, acc[r]);
        acc[r] = fmaf(xv.w, w3, acc[r]);
      }
    }
    float* dst = half ? xj0 : xi0;
    #pragma unroll
    for (int r = 0; r < 4; ++r) dst[(size_t)(r0 + r) * D + c] = acc[r];
  } else {
    const int g = (bid - 512) * 256 + t;     // 0..32767
    const int layer = g >> 14;
    const int rem = g & 16383;               // = c*D + k
    const int c = rem >> 7, k = rem & 127;
    const float* src = layer ? wm2 : wm1;
    _Float16* dst = layer ? weT2 : weT1;
    dst[rem] = (_Float16)src[(2 * D + k) * D + c];
  }
}

// ---------------------------------------------------------------------------
// K2: layer-0 edge kernel. R27: two rows/block (1024 blocks, same batch).
// R28: MASKED msg0 stores restored — R19's unconditionalization was based
// on a falsified theory (k_mid FETCH never moved); it cost ~32 MB of
// zero-writes per iteration. Garbage in masked rows is provably inert:
// MFMA columns are independent, fmaxf kills NaN, am=0 kills the value,
// copy-out and k_fin skip masked j. Thread map per row: c8=(t&15)*8,
// jr=t>>4, j=16p+jr.
// ---------------------------------------------------------------------------
__global__ __launch_bounds__(256) void k_edge0(
    const int* __restrict__ ei, const float* __restrict__ eattr,
    const float* __restrict__ wm0,
    const float* __restrict__ xi0, const float* __restrict__ xj0,
    _Float16* __restrict__ msg0, float* __restrict__ agg0) {
  const int row0 = blockIdx.x * 2;      // 1024 blocks
  const int b = row0 >> 7;
  const int t = threadIdx.x;
  const int c8 = (t & 15) * 8, jr = t >> 4;

  __shared__ float eb[2][N * 20];       // 2 x 10 KB; aliased by hp after use
  __shared__ float w_t[DE0][D];         // 8 KB, shared by both rows
  __shared__ float amask[2][N];
  __shared__ float xi_r[2][D];
  float* hp = &eb[0][0];                // [2][16][16][8] = 16 KB after matmul

  const float4* esrc0 = (const float4*)(eattr + (size_t)row0 * N * DE0);
  const float4* esrc1 = (const float4*)(eattr + (size_t)(row0 + 1) * N * DE0);
  const float4* wsrc = (const float4*)(wm0 + 2 * DN0 * D);
  #pragma unroll
  for (int u = 0; u < 2; ++u) {
    const int idx4 = u * 256 + t;
    const int j = idx4 >> 2;
    const int k4 = (idx4 & 3) * 4;
    *(float4*)&eb[0][j * 20 + k4] = esrc0[idx4];
    *(float4*)&eb[1][j * 20 + k4] = esrc1[idx4];
    ((float4*)&w_t[0][0])[idx4] = wsrc[idx4];
  }
  {
    const int rh = t >> 7, i = t & 127;
    amask[rh][i] = (float)ei[(size_t)(row0 + rh) * N + i];
    xi_r[rh][i] = xi0[(size_t)(row0 + rh) * D + i];
  }
  __syncthreads();

  const float* xjb = xj0 + (size_t)b * N * D;
  float acc8A[8] = {}, acc8B[8] = {};

  #pragma unroll
  for (int rr = 0; rr < 2; ++rr) {
    // --- K=16 matmul: acc[p][q] over j=16p+jr, c=c8+q (row rr) ---
    float acc[8][8] = {};
    #pragma unroll 4
    for (int k = 0; k < DE0; ++k) {
      float av[8];
      #pragma unroll
      for (int p = 0; p < 8; ++p) av[p] = eb[rr][(16 * p + jr) * 20 + k];
      const floatx4 wv0 = *(const floatx4*)&w_t[k][c8];
      const floatx4 wv1 = *(const floatx4*)&w_t[k][c8 + 4];
      #pragma unroll
      for (int p = 0; p < 8; ++p)
        #pragma unroll
        for (int q = 0; q < 4; ++q) {
          acc[p][q]     = fmaf(av[p], wv0[q], acc[p][q]);
          acc[p][4 + q] = fmaf(av[p], wv1[q], acc[p][4 + q]);
        }
    }

    // --- epilogue: relu+mask, half8 store (swizzled, UNMASKED only), agg ---
    float* acc8 = rr ? acc8B : acc8A;
    _Float16* mrow = msg0 + (size_t)(row0 + rr) * N * D;
    const floatx4 xiv0 = *(const floatx4*)&xi_r[rr][c8];
    const floatx4 xiv1 = *(const floatx4*)&xi_r[rr][c8 + 4];
    #pragma unroll
    for (int p = 0; p < 8; ++p) {
      const int j = 16 * p + jr;
      const float am = amask[rr][j];
      const floatx4 xjv0 = *(const floatx4*)&xjb[j * D + c8];
      const floatx4 xjv1 = *(const floatx4*)&xjb[j * D + c8 + 4];
      half8 hv;
      #pragma unroll
      for (int q = 0; q < 4; ++q) {
        float v0 = fmaxf(xiv0[q] + xjv0[q] + acc[p][q], 0.f) * am;
        float v1 = fmaxf(xiv1[q] + xjv1[q] + acc[p][4 + q], 0.f) * am;
        hv[q] = (_Float16)v0;
        hv[4 + q] = (_Float16)v1;
        acc8[q] += v0;
        acc8[4 + q] += v1;
      }
      if (am != 0.f)                    // R28: masked store
        *(half8*)&mrow[j * D + (((t & 15) ^ jr) << 3)] = hv;
    }
  }

  __syncthreads();                      // eb reads done -> safe to alias hp
  #pragma unroll
  for (int q = 0; q < 8; ++q) {
    hp[((jr * 16 + (t & 15)) * 8 + q)] = acc8A[q];
    hp[2048 + ((jr * 16 + (t & 15)) * 8 + q)] = acc8B[q];
  }
  __syncthreads();
  {
    const int half = t >> 7, c = t & 127;
    const float* hpr = hp + half * 2048;
    float s = 0.f;
    #pragma unroll
    for (int g = 0; g < 16; ++g) s += hpr[(g * 16 + (c >> 3)) * 8 + (c & 7)];
    agg0[(size_t)(row0 + half) * D + c] = s;
  }
}

// ---------------------------------------------------------------------------
// K3: batched node-0 + layer-1 projections. 4 rows/block (512 blocks).
//   x1  = relu(x0@Wx0 + agg0@Wa0 + bn0) ; xi1 = x1@Wi1+bm1 ; xj1 = x1@Wj1
// ---------------------------------------------------------------------------
__global__ __launch_bounds__(256) void k_node1(
    const float* __restrict__ x0, const float* __restrict__ agg0,
    const float* __restrict__ wn0, const float* __restrict__ bn0,
    const float* __restrict__ wm1, const float* __restrict__ bm1,
    float* __restrict__ x1, float* __restrict__ xi1, float* __restrict__ xj1) {
  const int r0 = blockIdx.x * 4;        // 512 blocks
  const int t = threadIdx.x;
  const int c = t & 127, rh = t >> 7;
  __shared__ float sIn[4][DN0];
  __shared__ float sAg[4][D];
  __shared__ float sX1[4][D];
  ((float*)sIn)[t] = x0[(size_t)r0 * DN0 + t];
  ((float2*)sAg)[t] = ((const float2*)(agg0 + (size_t)r0 * D))[t];
  __syncthreads();

  // node0: 2 rows per thread
  float acc[2];
  #pragma unroll
  for (int r = 0; r < 2; ++r) acc[r] = bn0[c];
  #pragma unroll 4
  for (int k4 = 0; k4 < DN0; k4 += 4) {
    const float* wb = wn0 + k4 * D + c;
    const float w0 = wb[0], w1 = wb[D], w2 = wb[2 * D], w3 = wb[3 * D];
    #pragma unroll
    for (int r = 0; r < 2; ++r) {
      const float4 xv = *(const float4*)&sIn[rh * 2 + r][k4];
      acc[r] = fmaf(xv.x, w0, acc[r]);
      acc[r] = fmaf(xv.y, w1, acc[r]);
      acc[r] = fmaf(xv.z, w2, acc[r]);
      acc[r] = fmaf(xv.w, w3, acc[r]);
    }
  }
  #pragma unroll 4
  for (int k4 = 0; k4 < D; k4 += 4) {
    const float* wb = wn0 + (DN0 + k4) * D + c;
    const float w0 = wb[0], w1 = wb[D], w2 = wb[2 * D], w3 = wb[3 * D];
    #pragma unroll
    for (int r = 0; r < 2; ++r) {
      const float4 xv = *(const float4*)&sAg[rh * 2 + r][k4];
      acc[r] = fmaf(xv.x, w0, acc[r]);
      acc[r] = fmaf(xv.y, w1, acc[r]);
      acc[r] = fmaf(xv.z, w2, acc[r]);
      acc[r] = fmaf(xv.w, w3, acc[r]);
    }
  }
  #pragma unroll
  for (int r = 0; r < 2; ++r) {
    const float v = fmaxf(acc[r], 0.f);
    sX1[rh * 2 + r][c] = v;
    x1[(size_t)(r0 + rh * 2 + r) * D + c] = v;
  }
  __syncthreads();

  // xi1 (rh=0, +bm1) / xj1 (rh=1): 4 rows per thread
  float a[4];
  #pragma unroll
  for (int r = 0; r < 4; ++r) a[r] = rh ? 0.f : bm1[c];
  const float* wh = wm1 + (size_t)rh * D * D;
  #pragma unroll 4
  for (int k4 = 0; k4 < D; k4 += 4) {
    const float* wb = wh + k4 * D + c;
    const float w0 = wb[0], w1 = wb[D], w2 = wb[2 * D], w3 = wb[3 * D];
    #pragma unroll
    for (int r = 0; r < 4; ++r) {
      const float4 xv = *(const float4*)&sX1[r][k4];
      a[r] = fmaf(xv.x, w0, a[r]);
      a[r] = fmaf(xv.y, w1, a[r]);
      a[r] = fmaf(xv.z, w2, a[r]);
      a[r] = fmaf(xv.w, w3, a[r]);
    }
  }
  float* dst = rh ? xj1 : xi1;
  #pragma unroll
  for (int r = 0; r < 4; ++r) dst[(size_t)(r0 + r) * D + c] = a[r];
}

// ---------------------------------------------------------------------------
// K4: fused layer-1+2 edge kernel. R25 form kept (2 rows/block, 1024 blocks)
// — best measured TOTAL; fixed costs (a1/a2 frags, barriers) amortize over
// 2 rows. Rows 2r/2r+1 share the batch. C/D layout (m74/m101):
// col(j)=lane&31, row(c)=(reg&3)+8*(reg>>2)+4*(lane>>5).
// NOTE (R28): masked msg0 rows contain garbage — provably inert (see K2).
// ---------------------------------------------------------------------------
__global__ __launch_bounds__(256, 2) void k_mid(
    const int* __restrict__ ei, const _Float16* __restrict__ weT1,
    const _Float16* __restrict__ weT2,
    const float* __restrict__ xi, const float* __restrict__ xj,
    _Float16* __restrict__ em,          // in: msg0 (swizzled), out: T2
    float* __restrict__ agg1) {
  const int row0 = blockIdx.x * 2;      // 1024 blocks, rows 2r and 2r+1
  const int b = row0 >> 7;              // row0 even -> same batch for both
  const int t = threadIdx.x;
  const int w = t >> 6;                 // c-tile base 32w
  const int lane = t & 63;
  const int l31 = lane & 31;
  const int l15 = lane & 15;
  const int hl = lane >> 5;             // k-half; c offset 4*hl

  __shared__ _Float16 sE0[N * D];       // 32 KB row0 (swizzled)
  __shared__ _Float16 sE1[N * D];       // 32 KB row1
  __shared__ float sMask[2][N];

  // --- async-stage both rows (linear copies of swizzled layout) ---
  const _Float16* gsrc0 = em + (size_t)row0 * N * D;
  const _Float16* gsrc1 = em + (size_t)(row0 + 1) * N * D;
  #pragma unroll
  for (int u = 0; u < 8; ++u) {
    const int seg = (u * 4 + w) * 512;  // wave-uniform base, 1 KB per instr
    gld16(gsrc0 + seg + lane * 8, &sE0[seg]);
  }
  #pragma unroll
  for (int u = 0; u < 8; ++u) {
    const int seg = (u * 4 + w) * 512;
    gld16(gsrc1 + seg + lane * 8, &sE1[seg]);
  }

  // --- pass-1 weight frags, loaded ONCE for both rows ---
  half8 a1[8];
  #pragma unroll
  for (int ks = 0; ks < 8; ++ks)
    a1[ks] = *(const half8*)(weT1 + (32 * w + l31) * D + 16 * ks + 8 * hl);

  // --- per-lane invariants (overlap staging) ---
  floatx4 xiv0[4], xiv1[4];
  #pragma unroll
  for (int g = 0; g < 4; ++g) {
    xiv0[g] = *(const floatx4*)&xi[(size_t)row0 * D + 32 * w + 8 * g + 4 * hl];
    xiv1[g] = *(const floatx4*)
        &xi[(size_t)(row0 + 1) * D + 32 * w + 8 * g + 4 * hl];
  }
  sMask[t >> 7][t & 127] = (float)ei[(size_t)(row0 + (t >> 7)) * N + (t & 127)];

  __syncthreads();                      // drains gld16; sMask visible

  float am0[4], am1[4];
  #pragma unroll
  for (int jt = 0; jt < 4; ++jt) {
    am0[jt] = sMask[0][32 * jt + l31];
    am1[jt] = sMask[1][32 * jt + l31];
  }

  // --- pass 1, both rows interleaved: 64 MFMA back-to-back per wave ---
  const floatx16 vzero = {0.f,0.f,0.f,0.f,0.f,0.f,0.f,0.f,
                          0.f,0.f,0.f,0.f,0.f,0.f,0.f,0.f};
  floatx16 accA[4], accB[4];
  #pragma unroll
  for (int jt = 0; jt < 4; ++jt) { accA[jt] = vzero; accB[jt] = vzero; }
  #pragma unroll
  for (int ks = 0; ks < 8; ++ks)
    #pragma unroll
    for (int jt = 0; jt < 4; ++jt) {
      const int bofs = (32 * jt + l31) * D + (((2 * ks + hl) ^ l15) << 3);
      const half8 bv0 = *(const half8*)&sE0[bofs];
      accA[jt] = __builtin_amdgcn_mfma_f32_32x32x16_f16(a1[ks], bv0, accA[jt], 0, 0, 0);
      const half8 bv1 = *(const half8*)&sE1[bofs];
      accB[jt] = __builtin_amdgcn_mfma_f32_32x32x16_f16(a1[ks], bv1, accB[jt], 0, 0, 0);
    }

  __syncthreads();                      // all pass-1 reads complete

  // --- epilogue row0: msg1 -> hacc, e_mid RMW in sE0 ---
  const float* xjb = xj + (size_t)b * N * D;
  {
    floatx4 hacc[4];
    #pragma unroll
    for (int g = 0; g < 4; ++g) hacc[g] = (floatx4){0.f, 0.f, 0.f, 0.f};
    #pragma unroll
    for (int jt = 0; jt < 4; ++jt) {
      const int j = 32 * jt + l31;      // j&15 == l15
      #pragma unroll
      for (int g = 0; g < 4; ++g) {
        const int cofs = 32 * w + 8 * g + 4 * hl;
        const int hidx = j * D + (((4 * w + g) ^ l15) << 3) + 4 * hl;
        const floatx4 xjv = *(const floatx4*)&xjb[j * D + cofs];
        const half4 m0 = *(const half4*)&sE0[hidx];
        half4 mid;
        floatx4 m1;
        #pragma unroll
        for (int r = 0; r < 4; ++r) {
          const float v = xiv0[g][r] + xjv[r] + accA[jt][4 * g + r];
          m1[r] = fmaxf(v, 0.f) * am0[jt];
          mid[r] = (_Float16)(0.5f * ((float)m0[r] + m1[r]));
        }
        *(half4*)&sE0[hidx] = mid;
        hacc[g] += m1;
      }
    }
    #pragma unroll
    for (int m = 1; m < 32; m <<= 1)
      #pragma unroll
      for (int g = 0; g < 4; ++g)
        #pragma unroll
        for (int r = 0; r < 4; ++r)
          hacc[g][r] += __shfl_xor(hacc[g][r], m, 64);
    if (l31 == 0) {
      #pragma unroll
      for (int g = 0; g < 4; ++g)
        *(floatx4*)&agg1[(size_t)row0 * D + 32 * w + 8 * g + 4 * hl] = hacc[g];
    }
  }
  // --- epilogue row1 (xj reads are L1-hot replays of row0's) ---
  {
    floatx4 hacc[4];
    #pragma unroll
    for (int g = 0; g < 4; ++g) hacc[g] = (floatx4){0.f, 0.f, 0.f, 0.f};
    #pragma unroll
    for (int jt = 0; jt < 4; ++jt) {
      const int j = 32 * jt + l31;
      #pragma unroll
      for (int g = 0; g < 4; ++g) {
        const int cofs = 32 * w + 8 * g + 4 * hl;
        const int hidx = j * D + (((4 * w + g) ^ l15) << 3) + 4 * hl;
        const floatx4 xjv = *(const floatx4*)&xjb[j * D + cofs];
        const half4 m0 = *(const half4*)&sE1[hidx];
        half4 mid;
        floatx4 m1;
        #pragma unroll
        for (int r = 0; r < 4; ++r) {
          const float v = xiv1[g][r] + xjv[r] + accB[jt][4 * g + r];
          m1[r] = fmaxf(v, 0.f) * am1[jt];
          mid[r] = (_Float16)(0.5f * ((float)m0[r] + m1[r]));
        }
        *(half4*)&sE1[hidx] = mid;
        hacc[g] += m1;
      }
    }
    #pragma unroll
    for (int m = 1; m < 32; m <<= 1)
      #pragma unroll
      for (int g = 0; g < 4; ++g)
        #pragma unroll
        for (int r = 0; r < 4; ++r)
          hacc[g][r] += __shfl_xor(hacc[g][r], m, 64);
    if (l31 == 0) {
      #pragma unroll
      for (int g = 0; g < 4; ++g)
        *(floatx4*)&agg1[(size_t)(row0 + 1) * D + 32 * w + 8 * g + 4 * hl] =
            hacc[g];
    }
  }

  // pass-2 weights (a1 dead -> regs reusable); once for both rows
  half8 a2[8];
  #pragma unroll
  for (int ks = 0; ks < 8; ++ks)
    a2[ks] = *(const half8*)(weT2 + (32 * w + l31) * D + 16 * ks + 8 * hl);

  __syncthreads();                      // e_mid (both rows) visible

  // --- pass 2, both rows interleaved ---
  #pragma unroll
  for (int jt = 0; jt < 4; ++jt) { accA[jt] = vzero; accB[jt] = vzero; }
  #pragma unroll
  for (int ks = 0; ks < 8; ++ks)
    #pragma unroll
    for (int jt = 0; jt < 4; ++jt) {
      const int bofs = (32 * jt + l31) * D + (((2 * ks + hl) ^ l15) << 3);
      const half8 bv0 = *(const half8*)&sE0[bofs];
      accA[jt] = __builtin_amdgcn_mfma_f32_32x32x16_f16(a2[ks], bv0, accA[jt], 0, 0, 0);
      const half8 bv1 = *(const half8*)&sE1[bofs];
      accB[jt] = __builtin_amdgcn_mfma_f32_32x32x16_f16(a2[ks], bv1, accB[jt], 0, 0, 0);
    }

  __syncthreads();                      // all pass-2 reads complete

  // --- deposit T2 into sE0/sE1 (same cell mapping) ---
  #pragma unroll
  for (int jt = 0; jt < 4; ++jt) {
    const int j = 32 * jt + l31;
    #pragma unroll
    for (int g = 0; g < 4; ++g) {
      const int hidx = j * D + (((4 * w + g) ^ l15) << 3) + 4 * hl;
      half4 tv0, tv1;
      #pragma unroll
      for (int r = 0; r < 4; ++r) {
        tv0[r] = (_Float16)accA[jt][4 * g + r];
        tv1[r] = (_Float16)accB[jt][4 * g + r];
      }
      *(half4*)&sE0[hidx] = tv0;
      *(half4*)&sE1[hidx] = tv1;
    }
  }

  __syncthreads();                      // T2 complete in LDS

  // --- copy-out both rows, unmasked j only (swizzled layout preserved) ---
  uint4* gdst0 = (uint4*)(em + (size_t)row0 * N * D);
  uint4* gdst1 = (uint4*)(em + (size_t)(row0 + 1) * N * D);
  const uint4* ls0 = (const uint4*)sE0;
  const uint4* ls1 = (const uint4*)sE1;
  #pragma unroll
  for (int u = 0; u < 8; ++u) {
    const int idx4 = u * 256 + t;
    const int j = u * 16 + (t >> 4);
    if (sMask[0][j] != 0.f) gdst0[idx4] = ls0[idx4];
    if (sMask[1][j] != 0.f) gdst1[idx4] = ls1[idx4];
  }
}

// ---------------------------------------------------------------------------
// K5: batched node-1 + layer-2 projections. 4 rows/block (512 blocks).
//   x_mid = 0.5*(x1 + relu(x1@Wx1 + agg1@Wa1 + bn1))   (LDS only)
//   xi2 = x_mid@Wi2 + bm2 ;  xj2 = x_mid@Wj2
// ---------------------------------------------------------------------------
__global__ __launch_bounds__(256) void k_node2(
    const float* __restrict__ x1, const float* __restrict__ agg1,
    const float* __restrict__ wn1, const float* __restrict__ bn1,
    const float* __restrict__ wm2, const float* __restrict__ bm2,
    float* __restrict__ xi2, float* __restrict__ xj2) {
  const int r0 = blockIdx.x * 4;        // 512 blocks
  const int t = threadIdx.x;
  const int c = t & 127, rh = t >> 7;
  __shared__ float sIn[4][D];
  __shared__ float sAg[4][D];
  __shared__ float sXm[4][D];
  ((float2*)sIn)[t] = ((const float2*)(x1 + (size_t)r0 * D))[t];
  ((float2*)sAg)[t] = ((const float2*)(agg1 + (size_t)r0 * D))[t];
  __syncthreads();

  float acc[2];
  #pragma unroll
  for (int r = 0; r < 2; ++r) acc[r] = bn1[c];
  #pragma unroll 4
  for (int k4 = 0; k4 < D; k4 += 4) {
    const float* wb = wn1 + k4 * D + c;
    const float w0 = wb[0], w1 = wb[D], w2 = wb[2 * D], w3 = wb[3 * D];
    #pragma unroll
    for (int r = 0; r < 2; ++r) {
      const float4 xv = *(const float4*)&sIn[rh * 2 + r][k4];
      acc[r] = fmaf(xv.x, w0, acc[r]);
      acc[r] = fmaf(xv.y, w1, acc[r]);
      acc[r] = fmaf(xv.z, w2, acc[r]);
      acc[r] = fmaf(xv.w, w3, acc[r]);
    }
  }
  #pragma unroll 4
  for (int k4 = 0; k4 < D; k4 += 4) {
    const float* wb = wn1 + (D + k4) * D + c;
    const float w0 = wb[0], w1 = wb[D], w2 = wb[2 * D], w3 = wb[3 * D];
    #pragma unroll
    for (int r = 0; r < 2; ++r) {
      const float4 xv = *(const float4*)&sAg[rh * 2 + r][k4];
      acc[r] = fmaf(xv.x, w0, acc[r]);
      acc[r] = fmaf(xv.y, w1, acc[r]);
      acc[r] = fmaf(xv.z, w2, acc[r]);
      acc[r] = fmaf(xv.w, w3, acc[r]);
    }
  }
  #pragma unroll
  for (int r = 0; r < 2; ++r) {
    const float v = 0.5f * (sIn[rh * 2 + r][c] + fmaxf(acc[r], 0.f));
    sXm[rh * 2 + r][c] = v;
  }
  __syncthreads();

  float a[4];
  #pragma unroll
  for (int r = 0; r < 4; ++r) a[r] = rh ? 0.f : bm2[c];
  const float* wh = wm2 + (size_t)rh * D * D;
  #pragma unroll 4
  for (int k4 = 0; k4 < D; k4 += 4) {
    const float* wb = wh + k4 * D + c;
    const float w0 = wb[0], w1 = wb[D], w2 = wb[2 * D], w3 = wb[3 * D];
    #pragma unroll
    for (int r = 0; r < 4; ++r) {
      const float4 xv = *(const float4*)&sXm[r][k4];
      a[r] = fmaf(xv.x, w0, a[r]);
      a[r] = fmaf(xv.y, w1, a[r]);
      a[r] = fmaf(xv.z, w2, a[r]);
      a[r] = fmaf(xv.w, w3, a[r]);
    }
  }
  float* dst = rh ? xj2 : xi2;
  #pragma unroll
  for (int r = 0; r < 4; ++r) dst[(size_t)(r0 + r) * D + c] = a[r];
}

// ---------------------------------------------------------------------------
// K6: final layer streaming. R26: two rows/block (1024 blocks, same batch) —
// the batch's xj panel is loaded ONCE for both rows; final reduce uses all
// 256 threads. msg2 = relu(xi2 + xj2 + T2)*A; rowsum over j. Masked skipped.
// ---------------------------------------------------------------------------
__global__ __launch_bounds__(256) void k_fin(
    const int* __restrict__ ei, const _Float16* __restrict__ t2,
    const float* __restrict__ xi, const float* __restrict__ xj,
    float* __restrict__ rowsum) {
  const int row0 = blockIdx.x * 2;      // 1024 blocks
  const int b = row0 >> 7;
  const int t = threadIdx.x;
  const int c8 = (t & 15) * 8, jr = t >> 4;

  __shared__ float sMask[2][N];
  __shared__ float hp[2][16][16][8];    // 16 KB
  sMask[t >> 7][t & 127] = (float)ei[(size_t)(row0 + (t >> 7)) * N + (t & 127)];
  float xivA[8], xivB[8];
  *(floatx4*)&xivA[0] = *(const floatx4*)&xi[(size_t)row0 * D + c8];
  *(floatx4*)&xivA[4] = *(const floatx4*)&xi[(size_t)row0 * D + c8 + 4];
  *(floatx4*)&xivB[0] = *(const floatx4*)&xi[(size_t)(row0 + 1) * D + c8];
  *(floatx4*)&xivB[4] = *(const floatx4*)&xi[(size_t)(row0 + 1) * D + c8 + 4];
  __syncthreads();

  const _Float16* srcA = t2 + (size_t)row0 * N * D;
  const _Float16* srcB = srcA + N * D;
  const float* xjb = xj + (size_t)b * N * D;
  float accA[8] = {}, accB[8] = {};
  #pragma unroll
  for (int u = 0; u < 8; ++u) {
    const int j = u * 16 + jr;           // j&15 == jr
    const bool mA = sMask[0][j] != 0.f;
    const bool mB = sMask[1][j] != 0.f;
    if (mA | mB) {
      // shared xj panel load (one per pair of rows)
      const floatx4 xj0 = *(const floatx4*)&xjb[j * D + c8];
      const floatx4 xj1 = *(const floatx4*)&xjb[j * D + c8 + 4];
      const int tofs = j * D + (((t & 15) ^ jr) << 3);
      if (mA) {
        const half8 tv = *(const half8*)(srcA + tofs);
        #pragma unroll
        for (int r = 0; r < 4; ++r) {
          accA[r]     += fmaxf(xivA[r] + xj0[r] + (float)tv[r], 0.f);
          accA[4 + r] += fmaxf(xivA[4 + r] + xj1[r] + (float)tv[4 + r], 0.f);
        }
      }
      if (mB) {
        const half8 tv = *(const half8*)(srcB + tofs);
        #pragma unroll
        for (int r = 0; r < 4; ++r) {
          accB[r]     += fmaxf(xivB[r] + xj0[r] + (float)tv[r], 0.f);
          accB[4 + r] += fmaxf(xivB[4 + r] + xj1[r] + (float)tv[4 + r], 0.f);
        }
      }
    }
  }
  #pragma unroll
  for (int k = 0; k < 8; ++k) {
    hp[0][jr][t & 15][k] = accA[k];
    hp[1][jr][t & 15][k] = accB[k];
  }
  __syncthreads();
  {
    const int half = t >> 7, c = t & 127;
    float s = 0.f;
    #pragma unroll
    for (int g = 0; g < 16; ++g) s += hp[half][g][c >> 3][c & 7];
    rowsum[(size_t)(row0 + half) * D + c] = s;
  }
}

// ---------------------------------------------------------------------------
// K7: head MLP. 16 blocks.
// ---------------------------------------------------------------------------
__global__ __launch_bounds__(128) void k_head(
    const float* __restrict__ rowsum,
    const float* __restrict__ w1, const float* __restrict__ b1,
    const float* __restrict__ w2, const float* __restrict__ b2,
    const float* __restrict__ w3, const float* __restrict__ b3,
    float* __restrict__ out) {
  const int b = blockIdx.x;
  const int c = threadIdx.x;
  __shared__ float hr[D], h1r[D], h2r[D];
  const float* rs = rowsum + (size_t)b * N * D;
  float s = 0.f;
  for (int i = 0; i < N; ++i) s += rs[i * D + c];
  hr[c] = s * (1.f / (N * N));
  __syncthreads();
  float a = b1[c];
  #pragma unroll 8
  for (int k = 0; k < D; ++k) a = fmaf(hr[k], w1[k * D + c], a);
  h1r[c] = fmaxf(a, 0.f);
  __syncthreads();
  a = b2[c];
  #pragma unroll 8
  for (int k = 0; k < D; ++k) a = fmaf(h1r[k], w2[k * D + c], a);
  h2r[c] = fmaxf(a, 0.f);
  __syncthreads();
  hr[c] = h2r[c] * w3[c];
  __syncthreads();
  if (c == 0) {
    float s2 = b3[0];
    for (int k = 0; k < D; ++k) s2 += hr[k];
    out[b] = s2;
  }
}

// ---------------------------------------------------------------------------
extern "C" void kernel_launch(void* const* d_in, const int* in_sizes, int n_in,
                              void* d_out, int out_size, void* d_ws, size_t ws_size,
                              hipStream_t stream) {
  const int*   ei  = (const int*)d_in[0];
  const float* x0  = (const float*)d_in[1];
  const float* ea  = (const float*)d_in[2];
  const float* wm0 = (const float*)d_in[3];
  const float* bm0 = (const float*)d_in[4];
  const float* wn0 = (const float*)d_in[5];
  const float* bn0 = (const float*)d_in[6];
  const float* wm1 = (const float*)d_in[7];
  const float* bm1 = (const float*)d_in[8];
  const float* wn1 = (const float*)d_in[9];
  const float* bn1 = (const float*)d_in[10];
  const float* wm2 = (const float*)d_in[11];
  const float* bm2 = (const float*)d_in[12];
  const float* wh1 = (const float*)d_in[15];
  const float* bh1 = (const float*)d_in[16];
  const float* wh2 = (const float*)d_in[17];
  const float* bh2 = (const float*)d_in[18];
  const float* wh3 = (const float*)d_in[19];
  const float* bh3 = (const float*)d_in[20];
  float* out = (float*)d_out;

  _Float16* msg0h = (_Float16*)d_ws;                 // [B,N,N,D] fp16: msg0 -> T2
  _Float16* weT1  = msg0h + (size_t)B * N * N * D;
  _Float16* weT2  = weT1 + D * D;
  float* f = (float*)(weT2 + D * D);
  size_t off = 0;
  const size_t R = (size_t)B * N * D;
  float* xi0  = f + off; off += R;
  float* xj0  = f + off; off += R;
  float* x1   = f + off; off += R;
  float* xi1  = f + off; off += R;
  float* xj1  = f + off; off += R;
  float* xi2  = f + off; off += R;
  float* xj2  = f + off; off += R;
  float* rsum = f + off; off += R;

  // agg scratch: rsum buffer is dead until k_fin, so it carries agg0
  // (k_edge0 -> k_node1) and then agg1 (k_mid -> k_node2). Stream order
  // guarantees each consumer reads before the next producer overwrites.
  float* aggS = rsum;

  const int rows = B * N;   // 2048
  k_pre  <<<512 + 128, 256, 0, stream>>>(x0, wm0, bm0, wm1, wm2,
                                         xi0, xj0, weT1, weT2);
  k_edge0<<<rows / 2, 256, 0, stream>>>(ei, ea, wm0, xi0, xj0, msg0h, aggS);
  k_node1<<<rows / 4, 256, 0, stream>>>(x0, aggS, wn0, bn0, wm1, bm1,
                                        x1, xi1, xj1);
  k_mid  <<<rows / 2, 256, 0, stream>>>(ei, weT1, weT2, xi1, xj1, msg0h,
                                        aggS);
  k_node2<<<rows / 4, 256, 0, stream>>>(x1, aggS, wn1, bn1, wm2, bm2,
                                        xi2, xj2);
  k_fin  <<<rows / 2, 256, 0, stream>>>(ei, msg0h, xi2, xj2, rsum);
  k_head <<<B,    128, 0, stream>>>(rsum, wh1, bh1, wh2, bh2, wh3, bh3, out);
}

// Round 15
// 216.900 us; speedup vs baseline: 1.0064x; 1.0064x over previous
//
#include <hip/hip_runtime.h>

constexpr int B = 16, N = 128, D = 128, DN0 = 64, DE0 = 16;

typedef _Float16 half8 __attribute__((ext_vector_type(8)));
typedef _Float16 half4 __attribute__((ext_vector_type(4)));
typedef float floatx4 __attribute__((ext_vector_type(4)));
typedef float floatx16 __attribute__((ext_vector_type(16)));

// async 16B global->LDS. msg0/T2 global layout is cell-swizzled
// (16B cell g of row j stored at g^(j&15)) so linear copies land
// conflict-free in LDS.
__device__ __forceinline__ void gld16(const _Float16* g, _Float16* l) {
  __builtin_amdgcn_global_load_lds(
      (const __attribute__((address_space(1))) void*)g,
      (__attribute__((address_space(3))) void*)l, 16, 0, 0);
}

// ---------------------------------------------------------------------------
// K1: merged prep. R21 (kept): xi0/xj0 BATCHED 4 rows/block (512 blocks).
// bid >= 512 (128 blocks): WeT transposes. Weights k-major (R15).
// ---------------------------------------------------------------------------
__global__ __launch_bounds__(256) void k_pre(
    const float* __restrict__ x, const float* __restrict__ wm0,
    const float* __restrict__ bm0, const float* __restrict__ wm1,
    const float* __restrict__ wm2,
    float* __restrict__ xi0, float* __restrict__ xj0,
    _Float16* __restrict__ weT1, _Float16* __restrict__ weT2) {
  const int bid = blockIdx.x;
  const int t = threadIdx.x;
  if (bid < 512) {
    const int r0 = bid * 4;
    const int half = t >> 7, c = t & 127;
    __shared__ float sX[4][DN0];
    ((float*)sX)[t] = x[(size_t)r0 * DN0 + t];
    __syncthreads();
    float acc[4];
    #pragma unroll
    for (int r = 0; r < 4; ++r) acc[r] = half ? 0.f : bm0[c];
    const float* wb0 = wm0 + half * DN0 * D;
    #pragma unroll 4
    for (int k4 = 0; k4 < DN0; k4 += 4) {
      const float* wb = wb0 + k4 * D + c;
      const float w0 = wb[0], w1 = wb[D], w2 = wb[2 * D], w3 = wb[3 * D];
      #pragma unroll
      for (int r = 0; r < 4; ++r) {
        const float4 xv = *(const float4*)&sX[r][k4];
        acc[r] = fmaf(xv.x, w0, acc[r]);
        acc[r] = fmaf(xv.y, w1, acc[r]);
        acc[r] = fmaf(xv.z, w2, acc[r]);
        acc[r] = fmaf(xv.w, w3, acc[r]);
      }
    }
    float* dst = half ? xj0 : xi0;
    #pragma unroll
    for (int r = 0; r < 4; ++r) dst[(size_t)(r0 + r) * D + c] = acc[r];
  } else {
    const int g = (bid - 512) * 256 + t;     // 0..32767
    const int layer = g >> 14;
    const int rem = g & 16383;               // = c*D + k
    const int c = rem >> 7, k = rem & 127;
    const float* src = layer ? wm2 : wm1;
    _Float16* dst = layer ? weT2 : weT1;
    dst[rem] = (_Float16)src[(2 * D + k) * D + c];
  }
}

// ---------------------------------------------------------------------------
// K2: layer-0 edge kernel. R27: two rows/block (1024 blocks, same batch) —
// We0 staged once for both rows; row1's xj0 panel reads are L1 replays;
// agg reduce uses all 256 threads. R29: UNCONDITIONAL msg0 stores restored
// (R28's masked stores measured neutral-to-negative: system isn't
// write-bound, divergent store path costs as much as it saves).
// Thread map per row: c8=(t&15)*8, jr=t>>4, j=16p+jr.
// ---------------------------------------------------------------------------
__global__ __launch_bounds__(256) void k_edge0(
    const int* __restrict__ ei, const float* __restrict__ eattr,
    const float* __restrict__ wm0,
    const float* __restrict__ xi0, const float* __restrict__ xj0,
    _Float16* __restrict__ msg0, float* __restrict__ agg0) {
  const int row0 = blockIdx.x * 2;      // 1024 blocks
  const int b = row0 >> 7;
  const int t = threadIdx.x;
  const int c8 = (t & 15) * 8, jr = t >> 4;

  __shared__ float eb[2][N * 20];       // 2 x 10 KB; aliased by hp after use
  __shared__ float w_t[DE0][D];         // 8 KB, shared by both rows
  __shared__ float amask[2][N];
  __shared__ float xi_r[2][D];
  float* hp = &eb[0][0];                // [2][16][16][8] = 16 KB after matmul

  const float4* esrc0 = (const float4*)(eattr + (size_t)row0 * N * DE0);
  const float4* esrc1 = (const float4*)(eattr + (size_t)(row0 + 1) * N * DE0);
  const float4* wsrc = (const float4*)(wm0 + 2 * DN0 * D);
  #pragma unroll
  for (int u = 0; u < 2; ++u) {
    const int idx4 = u * 256 + t;
    const int j = idx4 >> 2;
    const int k4 = (idx4 & 3) * 4;
    *(float4*)&eb[0][j * 20 + k4] = esrc0[idx4];
    *(float4*)&eb[1][j * 20 + k4] = esrc1[idx4];
    ((float4*)&w_t[0][0])[idx4] = wsrc[idx4];
  }
  {
    const int rh = t >> 7, i = t & 127;
    amask[rh][i] = (float)ei[(size_t)(row0 + rh) * N + i];
    xi_r[rh][i] = xi0[(size_t)(row0 + rh) * D + i];
  }
  __syncthreads();

  const float* xjb = xj0 + (size_t)b * N * D;
  float acc8A[8] = {}, acc8B[8] = {};

  #pragma unroll
  for (int rr = 0; rr < 2; ++rr) {
    // --- K=16 matmul: acc[p][q] over j=16p+jr, c=c8+q (row rr) ---
    float acc[8][8] = {};
    #pragma unroll 4
    for (int k = 0; k < DE0; ++k) {
      float av[8];
      #pragma unroll
      for (int p = 0; p < 8; ++p) av[p] = eb[rr][(16 * p + jr) * 20 + k];
      const floatx4 wv0 = *(const floatx4*)&w_t[k][c8];
      const floatx4 wv1 = *(const floatx4*)&w_t[k][c8 + 4];
      #pragma unroll
      for (int p = 0; p < 8; ++p)
        #pragma unroll
        for (int q = 0; q < 4; ++q) {
          acc[p][q]     = fmaf(av[p], wv0[q], acc[p][q]);
          acc[p][4 + q] = fmaf(av[p], wv1[q], acc[p][4 + q]);
        }
    }

    // --- epilogue: relu+mask, half8 store (swizzled, ALL rows), agg ---
    float* acc8 = rr ? acc8B : acc8A;
    _Float16* mrow = msg0 + (size_t)(row0 + rr) * N * D;
    const floatx4 xiv0 = *(const floatx4*)&xi_r[rr][c8];
    const floatx4 xiv1 = *(const floatx4*)&xi_r[rr][c8 + 4];
    #pragma unroll
    for (int p = 0; p < 8; ++p) {
      const int j = 16 * p + jr;
      const float am = amask[rr][j];
      const floatx4 xjv0 = *(const floatx4*)&xjb[j * D + c8];
      const floatx4 xjv1 = *(const floatx4*)&xjb[j * D + c8 + 4];
      half8 hv;
      #pragma unroll
      for (int q = 0; q < 4; ++q) {
        float v0 = fmaxf(xiv0[q] + xjv0[q] + acc[p][q], 0.f) * am;
        float v1 = fmaxf(xiv1[q] + xjv1[q] + acc[p][4 + q], 0.f) * am;
        hv[q] = (_Float16)v0;
        hv[4 + q] = (_Float16)v1;
        acc8[q] += v0;
        acc8[4 + q] += v1;
      }
      *(half8*)&mrow[j * D + (((t & 15) ^ jr) << 3)] = hv;
    }
  }

  __syncthreads();                      // eb reads done -> safe to alias hp
  #pragma unroll
  for (int q = 0; q < 8; ++q) {
    hp[((jr * 16 + (t & 15)) * 8 + q)] = acc8A[q];
    hp[2048 + ((jr * 16 + (t & 15)) * 8 + q)] = acc8B[q];
  }
  __syncthreads();
  {
    const int half = t >> 7, c = t & 127;
    const float* hpr = hp + half * 2048;
    float s = 0.f;
    #pragma unroll
    for (int g = 0; g < 16; ++g) s += hpr[(g * 16 + (c >> 3)) * 8 + (c & 7)];
    agg0[(size_t)(row0 + half) * D + c] = s;
  }
}

// ---------------------------------------------------------------------------
// K3: batched node-0 + layer-1 projections. 4 rows/block (512 blocks).
//   x1  = relu(x0@Wx0 + agg0@Wa0 + bn0) ; xi1 = x1@Wi1+bm1 ; xj1 = x1@Wj1
// ---------------------------------------------------------------------------
__global__ __launch_bounds__(256) void k_node1(
    const float* __restrict__ x0, const float* __restrict__ agg0,
    const float* __restrict__ wn0, const float* __restrict__ bn0,
    const float* __restrict__ wm1, const float* __restrict__ bm1,
    float* __restrict__ x1, float* __restrict__ xi1, float* __restrict__ xj1) {
  const int r0 = blockIdx.x * 4;        // 512 blocks
  const int t = threadIdx.x;
  const int c = t & 127, rh = t >> 7;
  __shared__ float sIn[4][DN0];
  __shared__ float sAg[4][D];
  __shared__ float sX1[4][D];
  ((float*)sIn)[t] = x0[(size_t)r0 * DN0 + t];
  ((float2*)sAg)[t] = ((const float2*)(agg0 + (size_t)r0 * D))[t];
  __syncthreads();

  // node0: 2 rows per thread
  float acc[2];
  #pragma unroll
  for (int r = 0; r < 2; ++r) acc[r] = bn0[c];
  #pragma unroll 4
  for (int k4 = 0; k4 < DN0; k4 += 4) {
    const float* wb = wn0 + k4 * D + c;
    const float w0 = wb[0], w1 = wb[D], w2 = wb[2 * D], w3 = wb[3 * D];
    #pragma unroll
    for (int r = 0; r < 2; ++r) {
      const float4 xv = *(const float4*)&sIn[rh * 2 + r][k4];
      acc[r] = fmaf(xv.x, w0, acc[r]);
      acc[r] = fmaf(xv.y, w1, acc[r]);
      acc[r] = fmaf(xv.z, w2, acc[r]);
      acc[r] = fmaf(xv.w, w3, acc[r]);
    }
  }
  #pragma unroll 4
  for (int k4 = 0; k4 < D; k4 += 4) {
    const float* wb = wn0 + (DN0 + k4) * D + c;
    const float w0 = wb[0], w1 = wb[D], w2 = wb[2 * D], w3 = wb[3 * D];
    #pragma unroll
    for (int r = 0; r < 2; ++r) {
      const float4 xv = *(const float4*)&sAg[rh * 2 + r][k4];
      acc[r] = fmaf(xv.x, w0, acc[r]);
      acc[r] = fmaf(xv.y, w1, acc[r]);
      acc[r] = fmaf(xv.z, w2, acc[r]);
      acc[r] = fmaf(xv.w, w3, acc[r]);
    }
  }
  #pragma unroll
  for (int r = 0; r < 2; ++r) {
    const float v = fmaxf(acc[r], 0.f);
    sX1[rh * 2 + r][c] = v;
    x1[(size_t)(r0 + rh * 2 + r) * D + c] = v;
  }
  __syncthreads();

  // xi1 (rh=0, +bm1) / xj1 (rh=1): 4 rows per thread
  float a[4];
  #pragma unroll
  for (int r = 0; r < 4; ++r) a[r] = rh ? 0.f : bm1[c];
  const float* wh = wm1 + (size_t)rh * D * D;
  #pragma unroll 4
  for (int k4 = 0; k4 < D; k4 += 4) {
    const float* wb = wh + k4 * D + c;
    const float w0 = wb[0], w1 = wb[D], w2 = wb[2 * D], w3 = wb[3 * D];
    #pragma unroll
    for (int r = 0; r < 4; ++r) {
      const float4 xv = *(const float4*)&sX1[r][k4];
      a[r] = fmaf(xv.x, w0, a[r]);
      a[r] = fmaf(xv.y, w1, a[r]);
      a[r] = fmaf(xv.z, w2, a[r]);
      a[r] = fmaf(xv.w, w3, a[r]);
    }
  }
  float* dst = rh ? xj1 : xi1;
  #pragma unroll
  for (int r = 0; r < 4; ++r) dst[(size_t)(r0 + r) * D + c] = a[r];
}

// ---------------------------------------------------------------------------
// K4: fused layer-1+2 edge kernel. R25 form kept (2 rows/block, 1024 blocks)
// — best measured TOTAL; fixed costs (a1/a2 frags, barriers) amortize over
// 2 rows. Rows 2r/2r+1 share the batch. C/D layout (m74/m101):
// col(j)=lane&31, row(c)=(reg&3)+8*(reg>>2)+4*(lane>>5).
// ---------------------------------------------------------------------------
__global__ __launch_bounds__(256, 2) void k_mid(
    const int* __restrict__ ei, const _Float16* __restrict__ weT1,
    const _Float16* __restrict__ weT2,
    const float* __restrict__ xi, const float* __restrict__ xj,
    _Float16* __restrict__ em,          // in: msg0 (swizzled), out: T2
    float* __restrict__ agg1) {
  const int row0 = blockIdx.x * 2;      // 1024 blocks, rows 2r and 2r+1
  const int b = row0 >> 7;              // row0 even -> same batch for both
  const int t = threadIdx.x;
  const int w = t >> 6;                 // c-tile base 32w
  const int lane = t & 63;
  const int l31 = lane & 31;
  const int l15 = lane & 15;
  const int hl = lane >> 5;             // k-half; c offset 4*hl

  __shared__ _Float16 sE0[N * D];       // 32 KB row0 (swizzled)
  __shared__ _Float16 sE1[N * D];       // 32 KB row1
  __shared__ float sMask[2][N];

  // --- async-stage both rows (linear copies of swizzled layout) ---
  const _Float16* gsrc0 = em + (size_t)row0 * N * D;
  const _Float16* gsrc1 = em + (size_t)(row0 + 1) * N * D;
  #pragma unroll
  for (int u = 0; u < 8; ++u) {
    const int seg = (u * 4 + w) * 512;  // wave-uniform base, 1 KB per instr
    gld16(gsrc0 + seg + lane * 8, &sE0[seg]);
  }
  #pragma unroll
  for (int u = 0; u < 8; ++u) {
    const int seg = (u * 4 + w) * 512;
    gld16(gsrc1 + seg + lane * 8, &sE1[seg]);
  }

  // --- pass-1 weight frags, loaded ONCE for both rows ---
  half8 a1[8];
  #pragma unroll
  for (int ks = 0; ks < 8; ++ks)
    a1[ks] = *(const half8*)(weT1 + (32 * w + l31) * D + 16 * ks + 8 * hl);

  // --- per-lane invariants (overlap staging) ---
  floatx4 xiv0[4], xiv1[4];
  #pragma unroll
  for (int g = 0; g < 4; ++g) {
    xiv0[g] = *(const floatx4*)&xi[(size_t)row0 * D + 32 * w + 8 * g + 4 * hl];
    xiv1[g] = *(const floatx4*)
        &xi[(size_t)(row0 + 1) * D + 32 * w + 8 * g + 4 * hl];
  }
  sMask[t >> 7][t & 127] = (float)ei[(size_t)(row0 + (t >> 7)) * N + (t & 127)];

  __syncthreads();                      // drains gld16; sMask visible

  float am0[4], am1[4];
  #pragma unroll
  for (int jt = 0; jt < 4; ++jt) {
    am0[jt] = sMask[0][32 * jt + l31];
    am1[jt] = sMask[1][32 * jt + l31];
  }

  // --- pass 1, both rows interleaved: 64 MFMA back-to-back per wave ---
  const floatx16 vzero = {0.f,0.f,0.f,0.f,0.f,0.f,0.f,0.f,
                          0.f,0.f,0.f,0.f,0.f,0.f,0.f,0.f};
  floatx16 accA[4], accB[4];
  #pragma unroll
  for (int jt = 0; jt < 4; ++jt) { accA[jt] = vzero; accB[jt] = vzero; }
  #pragma unroll
  for (int ks = 0; ks < 8; ++ks)
    #pragma unroll
    for (int jt = 0; jt < 4; ++jt) {
      const int bofs = (32 * jt + l31) * D + (((2 * ks + hl) ^ l15) << 3);
      const half8 bv0 = *(const half8*)&sE0[bofs];
      accA[jt] = __builtin_amdgcn_mfma_f32_32x32x16_f16(a1[ks], bv0, accA[jt], 0, 0, 0);
      const half8 bv1 = *(const half8*)&sE1[bofs];
      accB[jt] = __builtin_amdgcn_mfma_f32_32x32x16_f16(a1[ks], bv1, accB[jt], 0, 0, 0);
    }

  __syncthreads();                      // all pass-1 reads complete

  // --- epilogue row0: msg1 -> hacc, e_mid RMW in sE0 ---
  const float* xjb = xj + (size_t)b * N * D;
  {
    floatx4 hacc[4];
    #pragma unroll
    for (int g = 0; g < 4; ++g) hacc[g] = (floatx4){0.f, 0.f, 0.f, 0.f};
    #pragma unroll
    for (int jt = 0; jt < 4; ++jt) {
      const int j = 32 * jt + l31;      // j&15 == l15
      #pragma unroll
      for (int g = 0; g < 4; ++g) {
        const int cofs = 32 * w + 8 * g + 4 * hl;
        const int hidx = j * D + (((4 * w + g) ^ l15) << 3) + 4 * hl;
        const floatx4 xjv = *(const floatx4*)&xjb[j * D + cofs];
        const half4 m0 = *(const half4*)&sE0[hidx];
        half4 mid;
        floatx4 m1;
        #pragma unroll
        for (int r = 0; r < 4; ++r) {
          const float v = xiv0[g][r] + xjv[r] + accA[jt][4 * g + r];
          m1[r] = fmaxf(v, 0.f) * am0[jt];
          mid[r] = (_Float16)(0.5f * ((float)m0[r] + m1[r]));
        }
        *(half4*)&sE0[hidx] = mid;
        hacc[g] += m1;
      }
    }
    #pragma unroll
    for (int m = 1; m < 32; m <<= 1)
      #pragma unroll
      for (int g = 0; g < 4; ++g)
        #pragma unroll
        for (int r = 0; r < 4; ++r)
          hacc[g][r] += __shfl_xor(hacc[g][r], m, 64);
    if (l31 == 0) {
      #pragma unroll
      for (int g = 0; g < 4; ++g)
        *(floatx4*)&agg1[(size_t)row0 * D + 32 * w + 8 * g + 4 * hl] = hacc[g];
    }
  }
  // --- epilogue row1 (xj reads are L1-hot replays of row0's) ---
  {
    floatx4 hacc[4];
    #pragma unroll
    for (int g = 0; g < 4; ++g) hacc[g] = (floatx4){0.f, 0.f, 0.f, 0.f};
    #pragma unroll
    for (int jt = 0; jt < 4; ++jt) {
      const int j = 32 * jt + l31;
      #pragma unroll
      for (int g = 0; g < 4; ++g) {
        const int cofs = 32 * w + 8 * g + 4 * hl;
        const int hidx = j * D + (((4 * w + g) ^ l15) << 3) + 4 * hl;
        const floatx4 xjv = *(const floatx4*)&xjb[j * D + cofs];
        const half4 m0 = *(const half4*)&sE1[hidx];
        half4 mid;
        floatx4 m1;
        #pragma unroll
        for (int r = 0; r < 4; ++r) {
          const float v = xiv1[g][r] + xjv[r] + accB[jt][4 * g + r];
          m1[r] = fmaxf(v, 0.f) * am1[jt];
          mid[r] = (_Float16)(0.5f * ((float)m0[r] + m1[r]));
        }
        *(half4*)&sE1[hidx] = mid;
        hacc[g] += m1;
      }
    }
    #pragma unroll
    for (int m = 1; m < 32; m <<= 1)
      #pragma unroll
      for (int g = 0; g < 4; ++g)
        #pragma unroll
        for (int r = 0; r < 4; ++r)
          hacc[g][r] += __shfl_xor(hacc[g][r], m, 64);
    if (l31 == 0) {
      #pragma unroll
      for (int g = 0; g < 4; ++g)
        *(floatx4*)&agg1[(size_t)(row0 + 1) * D + 32 * w + 8 * g + 4 * hl] =
            hacc[g];
    }
  }

  // pass-2 weights (a1 dead -> regs reusable); once for both rows
  half8 a2[8];
  #pragma unroll
  for (int ks = 0; ks < 8; ++ks)
    a2[ks] = *(const half8*)(weT2 + (32 * w + l31) * D + 16 * ks + 8 * hl);

  __syncthreads();                      // e_mid (both rows) visible

  // --- pass 2, both rows interleaved ---
  #pragma unroll
  for (int jt = 0; jt < 4; ++jt) { accA[jt] = vzero; accB[jt] = vzero; }
  #pragma unroll
  for (int ks = 0; ks < 8; ++ks)
    #pragma unroll
    for (int jt = 0; jt < 4; ++jt) {
      const int bofs = (32 * jt + l31) * D + (((2 * ks + hl) ^ l15) << 3);
      const half8 bv0 = *(const half8*)&sE0[bofs];
      accA[jt] = __builtin_amdgcn_mfma_f32_32x32x16_f16(a2[ks], bv0, accA[jt], 0, 0, 0);
      const half8 bv1 = *(const half8*)&sE1[bofs];
      accB[jt] = __builtin_amdgcn_mfma_f32_32x32x16_f16(a2[ks], bv1, accB[jt], 0, 0, 0);
    }

  __syncthreads();                      // all pass-2 reads complete

  // --- deposit T2 into sE0/sE1 (same cell mapping) ---
  #pragma unroll
  for (int jt = 0; jt < 4; ++jt) {
    const int j = 32 * jt + l31;
    #pragma unroll
    for (int g = 0; g < 4; ++g) {
      const int hidx = j * D + (((4 * w + g) ^ l15) << 3) + 4 * hl;
      half4 tv0, tv1;
      #pragma unroll
      for (int r = 0; r < 4; ++r) {
        tv0[r] = (_Float16)accA[jt][4 * g + r];
        tv1[r] = (_Float16)accB[jt][4 * g + r];
      }
      *(half4*)&sE0[hidx] = tv0;
      *(half4*)&sE1[hidx] = tv1;
    }
  }

  __syncthreads();                      // T2 complete in LDS

  // --- copy-out both rows, unmasked j only (swizzled layout preserved) ---
  uint4* gdst0 = (uint4*)(em + (size_t)row0 * N * D);
  uint4* gdst1 = (uint4*)(em + (size_t)(row0 + 1) * N * D);
  const uint4* ls0 = (const uint4*)sE0;
  const uint4* ls1 = (const uint4*)sE1;
  #pragma unroll
  for (int u = 0; u < 8; ++u) {
    const int idx4 = u * 256 + t;
    const int j = u * 16 + (t >> 4);
    if (sMask[0][j] != 0.f) gdst0[idx4] = ls0[idx4];
    if (sMask[1][j] != 0.f) gdst1[idx4] = ls1[idx4];
  }
}

// ---------------------------------------------------------------------------
// K5: batched node-1 + layer-2 projections. 4 rows/block (512 blocks).
//   x_mid = 0.5*(x1 + relu(x1@Wx1 + agg1@Wa1 + bn1))   (LDS only)
//   xi2 = x_mid@Wi2 + bm2 ;  xj2 = x_mid@Wj2
// ---------------------------------------------------------------------------
__global__ __launch_bounds__(256) void k_node2(
    const float* __restrict__ x1, const float* __restrict__ agg1,
    const float* __restrict__ wn1, const float* __restrict__ bn1,
    const float* __restrict__ wm2, const float* __restrict__ bm2,
    float* __restrict__ xi2, float* __restrict__ xj2) {
  const int r0 = blockIdx.x * 4;        // 512 blocks
  const int t = threadIdx.x;
  const int c = t & 127, rh = t >> 7;
  __shared__ float sIn[4][D];
  __shared__ float sAg[4][D];
  __shared__ float sXm[4][D];
  ((float2*)sIn)[t] = ((const float2*)(x1 + (size_t)r0 * D))[t];
  ((float2*)sAg)[t] = ((const float2*)(agg1 + (size_t)r0 * D))[t];
  __syncthreads();

  float acc[2];
  #pragma unroll
  for (int r = 0; r < 2; ++r) acc[r] = bn1[c];
  #pragma unroll 4
  for (int k4 = 0; k4 < D; k4 += 4) {
    const float* wb = wn1 + k4 * D + c;
    const float w0 = wb[0], w1 = wb[D], w2 = wb[2 * D], w3 = wb[3 * D];
    #pragma unroll
    for (int r = 0; r < 2; ++r) {
      const float4 xv = *(const float4*)&sIn[rh * 2 + r][k4];
      acc[r] = fmaf(xv.x, w0, acc[r]);
      acc[r] = fmaf(xv.y, w1, acc[r]);
      acc[r] = fmaf(xv.z, w2, acc[r]);
      acc[r] = fmaf(xv.w, w3, acc[r]);
    }
  }
  #pragma unroll 4
  for (int k4 = 0; k4 < D; k4 += 4) {
    const float* wb = wn1 + (D + k4) * D + c;
    const float w0 = wb[0], w1 = wb[D], w2 = wb[2 * D], w3 = wb[3 * D];
    #pragma unroll
    for (int r = 0; r < 2; ++r) {
      const float4 xv = *(const float4*)&sAg[rh * 2 + r][k4];
      acc[r] = fmaf(xv.x, w0, acc[r]);
      acc[r] = fmaf(xv.y, w1, acc[r]);
      acc[r] = fmaf(xv.z, w2, acc[r]);
      acc[r] = fmaf(xv.w, w3, acc[r]);
    }
  }
  #pragma unroll
  for (int r = 0; r < 2; ++r) {
    const float v = 0.5f * (sIn[rh * 2 + r][c] + fmaxf(acc[r], 0.f));
    sXm[rh * 2 + r][c] = v;
  }
  __syncthreads();

  float a[4];
  #pragma unroll
  for (int r = 0; r < 4; ++r) a[r] = rh ? 0.f : bm2[c];
  const float* wh = wm2 + (size_t)rh * D * D;
  #pragma unroll 4
  for (int k4 = 0; k4 < D; k4 += 4) {
    const float* wb = wh + k4 * D + c;
    const float w0 = wb[0], w1 = wb[D], w2 = wb[2 * D], w3 = wb[3 * D];
    #pragma unroll
    for (int r = 0; r < 4; ++r) {
      const float4 xv = *(const float4*)&sXm[r][k4];
      a[r] = fmaf(xv.x, w0, a[r]);
      a[r] = fmaf(xv.y, w1, a[r]);
      a[r] = fmaf(xv.z, w2, a[r]);
      a[r] = fmaf(xv.w, w3, a[r]);
    }
  }
  float* dst = rh ? xj2 : xi2;
  #pragma unroll
  for (int r = 0; r < 4; ++r) dst[(size_t)(r0 + r) * D + c] = a[r];
}

// ---------------------------------------------------------------------------
// K6: final layer streaming. R26: two rows/block (1024 blocks, same batch) —
// the batch's xj panel is loaded ONCE for both rows; final reduce uses all
// 256 threads. msg2 = relu(xi2 + xj2 + T2)*A; rowsum over j. Masked skipped.
// ---------------------------------------------------------------------------
__global__ __launch_bounds__(256) void k_fin(
    const int* __restrict__ ei, const _Float16* __restrict__ t2,
    const float* __restrict__ xi, const float* __restrict__ xj,
    float* __restrict__ rowsum) {
  const int row0 = blockIdx.x * 2;      // 1024 blocks
  const int b = row0 >> 7;
  const int t = threadIdx.x;
  const int c8 = (t & 15) * 8, jr = t >> 4;

  __shared__ float sMask[2][N];
  __shared__ float hp[2][16][16][8];    // 16 KB
  sMask[t >> 7][t & 127] = (float)ei[(size_t)(row0 + (t >> 7)) * N + (t & 127)];
  float xivA[8], xivB[8];
  *(floatx4*)&xivA[0] = *(const floatx4*)&xi[(size_t)row0 * D + c8];
  *(floatx4*)&xivA[4] = *(const floatx4*)&xi[(size_t)row0 * D + c8 + 4];
  *(floatx4*)&xivB[0] = *(const floatx4*)&xi[(size_t)(row0 + 1) * D + c8];
  *(floatx4*)&xivB[4] = *(const floatx4*)&xi[(size_t)(row0 + 1) * D + c8 + 4];
  __syncthreads();

  const _Float16* srcA = t2 + (size_t)row0 * N * D;
  const _Float16* srcB = srcA + N * D;
  const float* xjb = xj + (size_t)b * N * D;
  float accA[8] = {}, accB[8] = {};
  #pragma unroll
  for (int u = 0; u < 8; ++u) {
    const int j = u * 16 + jr;           // j&15 == jr
    const bool mA = sMask[0][j] != 0.f;
    const bool mB = sMask[1][j] != 0.f;
    if (mA | mB) {
      // shared xj panel load (one per pair of rows)
      const floatx4 xj0 = *(const floatx4*)&xjb[j * D + c8];
      const floatx4 xj1 = *(const floatx4*)&xjb[j * D + c8 + 4];
      const int tofs = j * D + (((t & 15) ^ jr) << 3);
      if (mA) {
        const half8 tv = *(const half8*)(srcA + tofs);
        #pragma unroll
        for (int r = 0; r < 4; ++r) {
          accA[r]     += fmaxf(xivA[r] + xj0[r] + (float)tv[r], 0.f);
          accA[4 + r] += fmaxf(xivA[4 + r] + xj1[r] + (float)tv[4 + r], 0.f);
        }
      }
      if (mB) {
        const half8 tv = *(const half8*)(srcB + tofs);
        #pragma unroll
        for (int r = 0; r < 4; ++r) {
          accB[r]     += fmaxf(xivB[r] + xj0[r] + (float)tv[r], 0.f);
          accB[4 + r] += fmaxf(xivB[4 + r] + xj1[r] + (float)tv[4 + r], 0.f);
        }
      }
    }
  }
  #pragma unroll
  for (int k = 0; k < 8; ++k) {
    hp[0][jr][t & 15][k] = accA[k];
    hp[1][jr][t & 15][k] = accB[k];
  }
  __syncthreads();
  {
    const int half = t >> 7, c = t & 127;
    float s = 0.f;
    #pragma unroll
    for (int g = 0; g < 16; ++g) s += hp[half][g][c >> 3][c & 7];
    rowsum[(size_t)(row0 + half) * D + c] = s;
  }
}

// ---------------------------------------------------------------------------
// K7: head MLP. 16 blocks.
// ---------------------------------------------------------------------------
__global__ __launch_bounds__(128) void k_head(
    const float* __restrict__ rowsum,
    const float* __restrict__ w1, const float* __restrict__ b1,
    const float* __restrict__ w2, const float* __restrict__ b2,
    const float* __restrict__ w3, const float* __restrict__ b3,
    float* __restrict__ out) {
  const int b = blockIdx.x;
  const int c = threadIdx.x;
  __shared__ float hr[D], h1r[D], h2r[D];
  const float* rs = rowsum + (size_t)b * N * D;
  float s = 0.f;
  for (int i = 0; i < N; ++i) s += rs[i * D + c];
  hr[c] = s * (1.f / (N * N));
  __syncthreads();
  float a = b1[c];
  #pragma unroll 8
  for (int k = 0; k < D; ++k) a = fmaf(hr[k], w1[k * D + c], a);
  h1r[c] = fmaxf(a, 0.f);
  __syncthreads();
  a = b2[c];
  #pragma unroll 8
  for (int k = 0; k < D; ++k) a = fmaf(h1r[k], w2[k * D + c], a);
  h2r[c] = fmaxf(a, 0.f);
  __syncthreads();
  hr[c] = h2r[c] * w3[c];
  __syncthreads();
  if (c == 0) {
    float s2 = b3[0];
    for (int k = 0; k < D; ++k) s2 += hr[k];
    out[b] = s2;
  }
}

// ---------------------------------------------------------------------------
extern "C" void kernel_launch(void* const* d_in, const int* in_sizes, int n_in,
                              void* d_out, int out_size, void* d_ws, size_t ws_size,
                              hipStream_t stream) {
  const int*   ei  = (const int*)d_in[0];
  const float* x0  = (const float*)d_in[1];
  const float* ea  = (const float*)d_in[2];
  const float* wm0 = (const float*)d_in[3];
  const float* bm0 = (const float*)d_in[4];
  const float* wn0 = (const float*)d_in[5];
  const float* bn0 = (const float*)d_in[6];
  const float* wm1 = (const float*)d_in[7];
  const float* bm1 = (const float*)d_in[8];
  const float* wn1 = (const float*)d_in[9];
  const float* bn1 = (const float*)d_in[10];
  const float* wm2 = (const float*)d_in[11];
  const float* bm2 = (const float*)d_in[12];
  const float* wh1 = (const float*)d_in[15];
  const float* bh1 = (const float*)d_in[16];
  const float* wh2 = (const float*)d_in[17];
  const float* bh2 = (const float*)d_in[18];
  const float* wh3 = (const float*)d_in[19];
  const float* bh3 = (const float*)d_in[20];
  float* out = (float*)d_out;

  _Float16* msg0h = (_Float16*)d_ws;                 // [B,N,N,D] fp16: msg0 -> T2
  _Float16* weT1  = msg0h + (size_t)B * N * N * D;
  _Float16* weT2  = weT1 + D * D;
  float* f = (float*)(weT2 + D * D);
  size_t off = 0;
  const size_t R = (size_t)B * N * D;
  float* xi0  = f + off; off += R;
  float* xj0  = f + off; off += R;
  float* x1   = f + off; off += R;
  float* xi1  = f + off; off += R;
  float* xj1  = f + off; off += R;
  float* xi2  = f + off; off += R;
  float* xj2  = f + off; off += R;
  float* rsum = f + off; off += R;

  // agg scratch: rsum buffer is dead until k_fin, so it carries agg0
  // (k_edge0 -> k_node1) and then agg1 (k_mid -> k_node2). Stream order
  // guarantees each consumer reads before the next producer overwrites.
  float* aggS = rsum;

  const int rows = B * N;   // 2048
  k_pre  <<<512 + 128, 256, 0, stream>>>(x0, wm0, bm0, wm1, wm2,
                                         xi0, xj0, weT1, weT2);
  k_edge0<<<rows / 2, 256, 0, stream>>>(ei, ea, wm0, xi0, xj0, msg0h, aggS);
  k_node1<<<rows / 4, 256, 0, stream>>>(x0, aggS, wn0, bn0, wm1, bm1,
                                        x1, xi1, xj1);
  k_mid  <<<rows / 2, 256, 0, stream>>>(ei, weT1, weT2, xi1, xj1, msg0h,
                                        aggS);
  k_node2<<<rows / 4, 256, 0, stream>>>(x1, aggS, wn1, bn1, wm2, bm2,
                                        xi2, xj2);
  k_fin  <<<rows / 2, 256, 0, stream>>>(ei, msg0h, xi2, xj2, rsum);
  k_head <<<B,    128, 0, stream>>>(rsum, wh1, bh1, wh2, bh2, wh3, bh3, out);
}

// Round 16
// 210.896 us; speedup vs baseline: 1.0350x; 1.0285x over previous
//
#include <hip/hip_runtime.h>

constexpr int B = 16, N = 128, D = 128, DN0 = 64, DE0 = 16;

typedef _Float16 half8 __attribute__((ext_vector_type(8)));
typedef _Float16 half4 __attribute__((ext_vector_type(4)));
typedef float floatx4 __attribute__((ext_vector_type(4)));
typedef float floatx16 __attribute__((ext_vector_type(16)));

// async 16B global->LDS. msg0/T2 global layout is cell-swizzled
// (16B cell g of row j stored at g^(j&15)) so linear copies land
// conflict-free in LDS.
__device__ __forceinline__ void gld16(const _Float16* g, _Float16* l) {
  __builtin_amdgcn_global_load_lds(
      (const __attribute__((address_space(1))) void*)g,
      (__attribute__((address_space(3))) void*)l, 16, 0, 0);
}

// ---------------------------------------------------------------------------
// K1: merged prep. R21: xi0/xj0 BATCHED 4 rows/block (512 blocks).
// bid >= 512 (128 blocks): WeT transposes. Weights k-major (R15).
// ---------------------------------------------------------------------------
__global__ __launch_bounds__(256) void k_pre(
    const float* __restrict__ x, const float* __restrict__ wm0,
    const float* __restrict__ bm0, const float* __restrict__ wm1,
    const float* __restrict__ wm2,
    float* __restrict__ xi0, float* __restrict__ xj0,
    _Float16* __restrict__ weT1, _Float16* __restrict__ weT2) {
  const int bid = blockIdx.x;
  const int t = threadIdx.x;
  if (bid < 512) {
    const int r0 = bid * 4;
    const int half = t >> 7, c = t & 127;
    __shared__ float sX[4][DN0];
    ((float*)sX)[t] = x[(size_t)r0 * DN0 + t];
    __syncthreads();
    float acc[4];
    #pragma unroll
    for (int r = 0; r < 4; ++r) acc[r] = half ? 0.f : bm0[c];
    const float* wb0 = wm0 + half * DN0 * D;
    #pragma unroll 4
    for (int k4 = 0; k4 < DN0; k4 += 4) {
      const float* wb = wb0 + k4 * D + c;
      const float w0 = wb[0], w1 = wb[D], w2 = wb[2 * D], w3 = wb[3 * D];
      #pragma unroll
      for (int r = 0; r < 4; ++r) {
        const float4 xv = *(const float4*)&sX[r][k4];
        acc[r] = fmaf(xv.x, w0, acc[r]);
        acc[r] = fmaf(xv.y, w1, acc[r]);
        acc[r] = fmaf(xv.z, w2, acc[r]);
        acc[r] = fmaf(xv.w, w3, acc[r]);
      }
    }
    float* dst = half ? xj0 : xi0;
    #pragma unroll
    for (int r = 0; r < 4; ++r) dst[(size_t)(r0 + r) * D + c] = acc[r];
  } else {
    const int g = (bid - 512) * 256 + t;     // 0..32767
    const int layer = g >> 14;
    const int rem = g & 16383;               // = c*D + k
    const int c = rem >> 7, k = rem & 127;
    const float* src = layer ? wm2 : wm1;
    _Float16* dst = layer ? weT2 : weT1;
    dst[rem] = (_Float16)src[(2 * D + k) * D + c];
  }
}

// ---------------------------------------------------------------------------
// K2: layer-0 edge kernel. Unconditional msg0 stores (R19). Exports agg0.
// Thread map: c8=(t&15)*8, jr=t>>4, j=16p+jr.
// ---------------------------------------------------------------------------
__global__ __launch_bounds__(256) void k_edge0(
    const int* __restrict__ ei, const float* __restrict__ eattr,
    const float* __restrict__ wm0,
    const float* __restrict__ xi0, const float* __restrict__ xj0,
    _Float16* __restrict__ msg0, float* __restrict__ agg0) {
  const int row = blockIdx.x;
  const int b = row >> 7;
  const int t = threadIdx.x;
  const int c8 = (t & 15) * 8, jr = t >> 4;

  __shared__ float eb[N * 20];          // e_row [j][k] pad 20; aliased by hp
  __shared__ float w_t[DE0][D];
  __shared__ float amask[N];
  __shared__ float xi_r[D];
  float* hp = eb;                       // [16][16][8] after matmul (8 KB)

  const float4* esrc = (const float4*)(eattr + (size_t)row * N * DE0);
  const float4* wsrc = (const float4*)(wm0 + 2 * DN0 * D);
  #pragma unroll
  for (int u = 0; u < 2; ++u) {
    const int idx4 = u * 256 + t;
    const int j = idx4 >> 2;
    const int k4 = (idx4 & 3) * 4;
    *(float4*)&eb[j * 20 + k4] = esrc[idx4];
    ((float4*)&w_t[0][0])[idx4] = wsrc[idx4];
  }
  if (t < N) {
    amask[t] = (float)ei[(size_t)row * N + t];
    xi_r[t] = xi0[(size_t)row * D + t];
  }
  __syncthreads();

  // --- K=16 matmul: acc[p][q] over j=16p+jr, c=c8+q ---
  float acc[8][8] = {};
  #pragma unroll 4
  for (int k = 0; k < DE0; ++k) {
    float av[8];
    #pragma unroll
    for (int p = 0; p < 8; ++p) av[p] = eb[(16 * p + jr) * 20 + k];
    const floatx4 wv0 = *(const floatx4*)&w_t[k][c8];
    const floatx4 wv1 = *(const floatx4*)&w_t[k][c8 + 4];
    #pragma unroll
    for (int p = 0; p < 8; ++p)
      #pragma unroll
      for (int q = 0; q < 4; ++q) {
        acc[p][q]     = fmaf(av[p], wv0[q], acc[p][q]);
        acc[p][4 + q] = fmaf(av[p], wv1[q], acc[p][4 + q]);
      }
  }

  // --- epilogue: relu+mask, half8 store (swizzled, ALL rows), agg ---
  float acc8[8] = {};
  const float* xjb = xj0 + (size_t)b * N * D;
  _Float16* mrow = msg0 + (size_t)row * N * D;
  const floatx4 xiv0 = *(const floatx4*)&xi_r[c8];
  const floatx4 xiv1 = *(const floatx4*)&xi_r[c8 + 4];
  #pragma unroll
  for (int p = 0; p < 8; ++p) {
    const int j = 16 * p + jr;
    const float am = amask[j];
    const floatx4 xjv0 = *(const floatx4*)&xjb[j * D + c8];
    const floatx4 xjv1 = *(const floatx4*)&xjb[j * D + c8 + 4];
    half8 hv;
    #pragma unroll
    for (int q = 0; q < 4; ++q) {
      float v0 = fmaxf(xiv0[q] + xjv0[q] + acc[p][q], 0.f) * am;
      float v1 = fmaxf(xiv1[q] + xjv1[q] + acc[p][4 + q], 0.f) * am;
      hv[q] = (_Float16)v0;
      hv[4 + q] = (_Float16)v1;
      acc8[q] += v0;
      acc8[4 + q] += v1;
    }
    *(half8*)&mrow[j * D + (((t & 15) ^ jr) << 3)] = hv;
  }

  __syncthreads();                      // eb reads done -> safe to alias hp
  #pragma unroll
  for (int q = 0; q < 8; ++q) hp[(jr * 16 + (t & 15)) * 8 + q] = acc8[q];
  __syncthreads();
  if (t < D) {
    float s = 0.f;
    #pragma unroll
    for (int g = 0; g < 16; ++g) s += hp[(g * 16 + (t >> 3)) * 8 + (t & 7)];
    agg0[(size_t)row * D + t] = s;
  }
}

// ---------------------------------------------------------------------------
// K3: batched node-0 + layer-1 projections. 4 rows/block (512 blocks).
//   x1  = relu(x0@Wx0 + agg0@Wa0 + bn0) ; xi1 = x1@Wi1+bm1 ; xj1 = x1@Wj1
// ---------------------------------------------------------------------------
__global__ __launch_bounds__(256) void k_node1(
    const float* __restrict__ x0, const float* __restrict__ agg0,
    const float* __restrict__ wn0, const float* __restrict__ bn0,
    const float* __restrict__ wm1, const float* __restrict__ bm1,
    float* __restrict__ x1, float* __restrict__ xi1, float* __restrict__ xj1) {
  const int r0 = blockIdx.x * 4;        // 512 blocks
  const int t = threadIdx.x;
  const int c = t & 127, rh = t >> 7;
  __shared__ float sIn[4][DN0];
  __shared__ float sAg[4][D];
  __shared__ float sX1[4][D];
  ((float*)sIn)[t] = x0[(size_t)r0 * DN0 + t];
  ((float2*)sAg)[t] = ((const float2*)(agg0 + (size_t)r0 * D))[t];
  __syncthreads();

  // node0: 2 rows per thread
  float acc[2];
  #pragma unroll
  for (int r = 0; r < 2; ++r) acc[r] = bn0[c];
  #pragma unroll 4
  for (int k4 = 0; k4 < DN0; k4 += 4) {
    const float* wb = wn0 + k4 * D + c;
    const float w0 = wb[0], w1 = wb[D], w2 = wb[2 * D], w3 = wb[3 * D];
    #pragma unroll
    for (int r = 0; r < 2; ++r) {
      const float4 xv = *(const float4*)&sIn[rh * 2 + r][k4];
      acc[r] = fmaf(xv.x, w0, acc[r]);
      acc[r] = fmaf(xv.y, w1, acc[r]);
      acc[r] = fmaf(xv.z, w2, acc[r]);
      acc[r] = fmaf(xv.w, w3, acc[r]);
    }
  }
  #pragma unroll 4
  for (int k4 = 0; k4 < D; k4 += 4) {
    const float* wb = wn0 + (DN0 + k4) * D + c;
    const float w0 = wb[0], w1 = wb[D], w2 = wb[2 * D], w3 = wb[3 * D];
    #pragma unroll
    for (int r = 0; r < 2; ++r) {
      const float4 xv = *(const float4*)&sAg[rh * 2 + r][k4];
      acc[r] = fmaf(xv.x, w0, acc[r]);
      acc[r] = fmaf(xv.y, w1, acc[r]);
      acc[r] = fmaf(xv.z, w2, acc[r]);
      acc[r] = fmaf(xv.w, w3, acc[r]);
    }
  }
  #pragma unroll
  for (int r = 0; r < 2; ++r) {
    const float v = fmaxf(acc[r], 0.f);
    sX1[rh * 2 + r][c] = v;
    x1[(size_t)(r0 + rh * 2 + r) * D + c] = v;
  }
  __syncthreads();

  // xi1 (rh=0, +bm1) / xj1 (rh=1): 4 rows per thread
  float a[4];
  #pragma unroll
  for (int r = 0; r < 4; ++r) a[r] = rh ? 0.f : bm1[c];
  const float* wh = wm1 + (size_t)rh * D * D;
  #pragma unroll 4
  for (int k4 = 0; k4 < D; k4 += 4) {
    const float* wb = wh + k4 * D + c;
    const float w0 = wb[0], w1 = wb[D], w2 = wb[2 * D], w3 = wb[3 * D];
    #pragma unroll
    for (int r = 0; r < 4; ++r) {
      const float4 xv = *(const float4*)&sX1[r][k4];
      a[r] = fmaf(xv.x, w0, a[r]);
      a[r] = fmaf(xv.y, w1, a[r]);
      a[r] = fmaf(xv.z, w2, a[r]);
      a[r] = fmaf(xv.w, w3, a[r]);
    }
  }
  float* dst = rh ? xj1 : xi1;
  #pragma unroll
  for (int r = 0; r < 4; ++r) dst[(size_t)(r0 + r) * D + c] = a[r];
}

// ---------------------------------------------------------------------------
// K4: fused layer-1+2 edge kernel. R25: TWO ROWS PER BLOCK (1024 blocks) —
// fixed costs (a1/a2 frag loads, xiv/mask loads, 5 barriers, staging issue)
// amortize over 2x MFMA. Rows 2r/2r+1 share the batch; row1's xj panel
// reads are L1 replays. Best measured total (212.4 us). C/D layout
// (m74/m101): col(j)=lane&31, row(c)=(reg&3)+8*(reg>>2)+4*(lane>>5).
// ---------------------------------------------------------------------------
__global__ __launch_bounds__(256, 2) void k_mid(
    const int* __restrict__ ei, const _Float16* __restrict__ weT1,
    const _Float16* __restrict__ weT2,
    const float* __restrict__ xi, const float* __restrict__ xj,
    _Float16* __restrict__ em,          // in: msg0 (swizzled), out: T2
    float* __restrict__ agg1) {
  const int row0 = blockIdx.x * 2;      // 1024 blocks, rows 2r and 2r+1
  const int b = row0 >> 7;              // row0 even -> same batch for both
  const int t = threadIdx.x;
  const int w = t >> 6;                 // c-tile base 32w
  const int lane = t & 63;
  const int l31 = lane & 31;
  const int l15 = lane & 15;
  const int hl = lane >> 5;             // k-half; c offset 4*hl

  __shared__ _Float16 sE0[N * D];       // 32 KB row0 (swizzled)
  __shared__ _Float16 sE1[N * D];       // 32 KB row1
  __shared__ float sMask[2][N];

  // --- async-stage both rows (linear copies of swizzled layout) ---
  const _Float16* gsrc0 = em + (size_t)row0 * N * D;
  const _Float16* gsrc1 = em + (size_t)(row0 + 1) * N * D;
  #pragma unroll
  for (int u = 0; u < 8; ++u) {
    const int seg = (u * 4 + w) * 512;  // wave-uniform base, 1 KB per instr
    gld16(gsrc0 + seg + lane * 8, &sE0[seg]);
  }
  #pragma unroll
  for (int u = 0; u < 8; ++u) {
    const int seg = (u * 4 + w) * 512;
    gld16(gsrc1 + seg + lane * 8, &sE1[seg]);
  }

  // --- pass-1 weight frags, loaded ONCE for both rows ---
  half8 a1[8];
  #pragma unroll
  for (int ks = 0; ks < 8; ++ks)
    a1[ks] = *(const half8*)(weT1 + (32 * w + l31) * D + 16 * ks + 8 * hl);

  // --- per-lane invariants (overlap staging) ---
  floatx4 xiv0[4], xiv1[4];
  #pragma unroll
  for (int g = 0; g < 4; ++g) {
    xiv0[g] = *(const floatx4*)&xi[(size_t)row0 * D + 32 * w + 8 * g + 4 * hl];
    xiv1[g] = *(const floatx4*)
        &xi[(size_t)(row0 + 1) * D + 32 * w + 8 * g + 4 * hl];
  }
  sMask[t >> 7][t & 127] = (float)ei[(size_t)(row0 + (t >> 7)) * N + (t & 127)];

  __syncthreads();                      // drains gld16; sMask visible

  float am0[4], am1[4];
  #pragma unroll
  for (int jt = 0; jt < 4; ++jt) {
    am0[jt] = sMask[0][32 * jt + l31];
    am1[jt] = sMask[1][32 * jt + l31];
  }

  // --- pass 1, both rows interleaved: 64 MFMA back-to-back per wave ---
  const floatx16 vzero = {0.f,0.f,0.f,0.f,0.f,0.f,0.f,0.f,
                          0.f,0.f,0.f,0.f,0.f,0.f,0.f,0.f};
  floatx16 accA[4], accB[4];
  #pragma unroll
  for (int jt = 0; jt < 4; ++jt) { accA[jt] = vzero; accB[jt] = vzero; }
  #pragma unroll
  for (int ks = 0; ks < 8; ++ks)
    #pragma unroll
    for (int jt = 0; jt < 4; ++jt) {
      const int bofs = (32 * jt + l31) * D + (((2 * ks + hl) ^ l15) << 3);
      const half8 bv0 = *(const half8*)&sE0[bofs];
      accA[jt] = __builtin_amdgcn_mfma_f32_32x32x16_f16(a1[ks], bv0, accA[jt], 0, 0, 0);
      const half8 bv1 = *(const half8*)&sE1[bofs];
      accB[jt] = __builtin_amdgcn_mfma_f32_32x32x16_f16(a1[ks], bv1, accB[jt], 0, 0, 0);
    }

  __syncthreads();                      // all pass-1 reads complete

  // --- epilogue row0: msg1 -> hacc, e_mid RMW in sE0 ---
  const float* xjb = xj + (size_t)b * N * D;
  {
    floatx4 hacc[4];
    #pragma unroll
    for (int g = 0; g < 4; ++g) hacc[g] = (floatx4){0.f, 0.f, 0.f, 0.f};
    #pragma unroll
    for (int jt = 0; jt < 4; ++jt) {
      const int j = 32 * jt + l31;      // j&15 == l15
      #pragma unroll
      for (int g = 0; g < 4; ++g) {
        const int cofs = 32 * w + 8 * g + 4 * hl;
        const int hidx = j * D + (((4 * w + g) ^ l15) << 3) + 4 * hl;
        const floatx4 xjv = *(const floatx4*)&xjb[j * D + cofs];
        const half4 m0 = *(const half4*)&sE0[hidx];
        half4 mid;
        floatx4 m1;
        #pragma unroll
        for (int r = 0; r < 4; ++r) {
          const float v = xiv0[g][r] + xjv[r] + accA[jt][4 * g + r];
          m1[r] = fmaxf(v, 0.f) * am0[jt];
          mid[r] = (_Float16)(0.5f * ((float)m0[r] + m1[r]));
        }
        *(half4*)&sE0[hidx] = mid;
        hacc[g] += m1;
      }
    }
    #pragma unroll
    for (int m = 1; m < 32; m <<= 1)
      #pragma unroll
      for (int g = 0; g < 4; ++g)
        #pragma unroll
        for (int r = 0; r < 4; ++r)
          hacc[g][r] += __shfl_xor(hacc[g][r], m, 64);
    if (l31 == 0) {
      #pragma unroll
      for (int g = 0; g < 4; ++g)
        *(floatx4*)&agg1[(size_t)row0 * D + 32 * w + 8 * g + 4 * hl] = hacc[g];
    }
  }
  // --- epilogue row1 (xj reads are L1-hot replays of row0's) ---
  {
    floatx4 hacc[4];
    #pragma unroll
    for (int g = 0; g < 4; ++g) hacc[g] = (floatx4){0.f, 0.f, 0.f, 0.f};
    #pragma unroll
    for (int jt = 0; jt < 4; ++jt) {
      const int j = 32 * jt + l31;
      #pragma unroll
      for (int g = 0; g < 4; ++g) {
        const int cofs = 32 * w + 8 * g + 4 * hl;
        const int hidx = j * D + (((4 * w + g) ^ l15) << 3) + 4 * hl;
        const floatx4 xjv = *(const floatx4*)&xjb[j * D + cofs];
        const half4 m0 = *(const half4*)&sE1[hidx];
        half4 mid;
        floatx4 m1;
        #pragma unroll
        for (int r = 0; r < 4; ++r) {
          const float v = xiv1[g][r] + xjv[r] + accB[jt][4 * g + r];
          m1[r] = fmaxf(v, 0.f) * am1[jt];
          mid[r] = (_Float16)(0.5f * ((float)m0[r] + m1[r]));
        }
        *(half4*)&sE1[hidx] = mid;
        hacc[g] += m1;
      }
    }
    #pragma unroll
    for (int m = 1; m < 32; m <<= 1)
      #pragma unroll
      for (int g = 0; g < 4; ++g)
        #pragma unroll
        for (int r = 0; r < 4; ++r)
          hacc[g][r] += __shfl_xor(hacc[g][r], m, 64);
    if (l31 == 0) {
      #pragma unroll
      for (int g = 0; g < 4; ++g)
        *(floatx4*)&agg1[(size_t)(row0 + 1) * D + 32 * w + 8 * g + 4 * hl] =
            hacc[g];
    }
  }

  // pass-2 weights (a1 dead -> regs reusable); once for both rows
  half8 a2[8];
  #pragma unroll
  for (int ks = 0; ks < 8; ++ks)
    a2[ks] = *(const half8*)(weT2 + (32 * w + l31) * D + 16 * ks + 8 * hl);

  __syncthreads();                      // e_mid (both rows) visible

  // --- pass 2, both rows interleaved ---
  #pragma unroll
  for (int jt = 0; jt < 4; ++jt) { accA[jt] = vzero; accB[jt] = vzero; }
  #pragma unroll
  for (int ks = 0; ks < 8; ++ks)
    #pragma unroll
    for (int jt = 0; jt < 4; ++jt) {
      const int bofs = (32 * jt + l31) * D + (((2 * ks + hl) ^ l15) << 3);
      const half8 bv0 = *(const half8*)&sE0[bofs];
      accA[jt] = __builtin_amdgcn_mfma_f32_32x32x16_f16(a2[ks], bv0, accA[jt], 0, 0, 0);
      const half8 bv1 = *(const half8*)&sE1[bofs];
      accB[jt] = __builtin_amdgcn_mfma_f32_32x32x16_f16(a2[ks], bv1, accB[jt], 0, 0, 0);
    }

  __syncthreads();                      // all pass-2 reads complete

  // --- deposit T2 into sE0/sE1 (same cell mapping) ---
  #pragma unroll
  for (int jt = 0; jt < 4; ++jt) {
    const int j = 32 * jt + l31;
    #pragma unroll
    for (int g = 0; g < 4; ++g) {
      const int hidx = j * D + (((4 * w + g) ^ l15) << 3) + 4 * hl;
      half4 tv0, tv1;
      #pragma unroll
      for (int r = 0; r < 4; ++r) {
        tv0[r] = (_Float16)accA[jt][4 * g + r];
        tv1[r] = (_Float16)accB[jt][4 * g + r];
      }
      *(half4*)&sE0[hidx] = tv0;
      *(half4*)&sE1[hidx] = tv1;
    }
  }

  __syncthreads();                      // T2 complete in LDS

  // --- copy-out both rows, unmasked j only (swizzled layout preserved) ---
  uint4* gdst0 = (uint4*)(em + (size_t)row0 * N * D);
  uint4* gdst1 = (uint4*)(em + (size_t)(row0 + 1) * N * D);
  const uint4* ls0 = (const uint4*)sE0;
  const uint4* ls1 = (const uint4*)sE1;
  #pragma unroll
  for (int u = 0; u < 8; ++u) {
    const int idx4 = u * 256 + t;
    const int j = u * 16 + (t >> 4);
    if (sMask[0][j] != 0.f) gdst0[idx4] = ls0[idx4];
    if (sMask[1][j] != 0.f) gdst1[idx4] = ls1[idx4];
  }
}

// ---------------------------------------------------------------------------
// K5: batched node-1 + layer-2 projections. 4 rows/block (512 blocks).
//   x_mid = 0.5*(x1 + relu(x1@Wx1 + agg1@Wa1 + bn1))   (LDS only)
//   xi2 = x_mid@Wi2 + bm2 ;  xj2 = x_mid@Wj2
// ---------------------------------------------------------------------------
__global__ __launch_bounds__(256) void k_node2(
    const float* __restrict__ x1, const float* __restrict__ agg1,
    const float* __restrict__ wn1, const float* __restrict__ bn1,
    const float* __restrict__ wm2, const float* __restrict__ bm2,
    float* __restrict__ xi2, float* __restrict__ xj2) {
  const int r0 = blockIdx.x * 4;        // 512 blocks
  const int t = threadIdx.x;
  const int c = t & 127, rh = t >> 7;
  __shared__ float sIn[4][D];
  __shared__ float sAg[4][D];
  __shared__ float sXm[4][D];
  ((float2*)sIn)[t] = ((const float2*)(x1 + (size_t)r0 * D))[t];
  ((float2*)sAg)[t] = ((const float2*)(agg1 + (size_t)r0 * D))[t];
  __syncthreads();

  float acc[2];
  #pragma unroll
  for (int r = 0; r < 2; ++r) acc[r] = bn1[c];
  #pragma unroll 4
  for (int k4 = 0; k4 < D; k4 += 4) {
    const float* wb = wn1 + k4 * D + c;
    const float w0 = wb[0], w1 = wb[D], w2 = wb[2 * D], w3 = wb[3 * D];
    #pragma unroll
    for (int r = 0; r < 2; ++r) {
      const float4 xv = *(const float4*)&sIn[rh * 2 + r][k4];
      acc[r] = fmaf(xv.x, w0, acc[r]);
      acc[r] = fmaf(xv.y, w1, acc[r]);
      acc[r] = fmaf(xv.z, w2, acc[r]);
      acc[r] = fmaf(xv.w, w3, acc[r]);
    }
  }
  #pragma unroll 4
  for (int k4 = 0; k4 < D; k4 += 4) {
    const float* wb = wn1 + (D + k4) * D + c;
    const float w0 = wb[0], w1 = wb[D], w2 = wb[2 * D], w3 = wb[3 * D];
    #pragma unroll
    for (int r = 0; r < 2; ++r) {
      const float4 xv = *(const float4*)&sAg[rh * 2 + r][k4];
      acc[r] = fmaf(xv.x, w0, acc[r]);
      acc[r] = fmaf(xv.y, w1, acc[r]);
      acc[r] = fmaf(xv.z, w2, acc[r]);
      acc[r] = fmaf(xv.w, w3, acc[r]);
    }
  }
  #pragma unroll
  for (int r = 0; r < 2; ++r) {
    const float v = 0.5f * (sIn[rh * 2 + r][c] + fmaxf(acc[r], 0.f));
    sXm[rh * 2 + r][c] = v;
  }
  __syncthreads();

  float a[4];
  #pragma unroll
  for (int r = 0; r < 4; ++r) a[r] = rh ? 0.f : bm2[c];
  const float* wh = wm2 + (size_t)rh * D * D;
  #pragma unroll 4
  for (int k4 = 0; k4 < D; k4 += 4) {
    const float* wb = wh + k4 * D + c;
    const float w0 = wb[0], w1 = wb[D], w2 = wb[2 * D], w3 = wb[3 * D];
    #pragma unroll
    for (int r = 0; r < 4; ++r) {
      const float4 xv = *(const float4*)&sXm[r][k4];
      a[r] = fmaf(xv.x, w0, a[r]);
      a[r] = fmaf(xv.y, w1, a[r]);
      a[r] = fmaf(xv.z, w2, a[r]);
      a[r] = fmaf(xv.w, w3, a[r]);
    }
  }
  float* dst = rh ? xj2 : xi2;
  #pragma unroll
  for (int r = 0; r < 4; ++r) dst[(size_t)(r0 + r) * D + c] = a[r];
}

// ---------------------------------------------------------------------------
// K6: final layer streaming: msg2 = relu(xi2 + xj2 + T2)*A; rowsum over j.
// Masked j rows skipped entirely (contribution 0; saves their 256 B loads).
// ---------------------------------------------------------------------------
__global__ __launch_bounds__(256) void k_fin(
    const int* __restrict__ ei, const _Float16* __restrict__ t2,
    const float* __restrict__ xi, const float* __restrict__ xj,
    float* __restrict__ rowsum) {
  const int row = blockIdx.x;
  const int b = row >> 7;
  const int t = threadIdx.x;
  const int c8 = (t & 15) * 8, jr = t >> 4;

  __shared__ float sMask[N];
  __shared__ float hp[16][16][8];
  if (t < N) sMask[t] = (float)ei[(size_t)row * N + t];
  float xiv[8];
  *(floatx4*)&xiv[0] = *(const floatx4*)&xi[row * D + c8];
  *(floatx4*)&xiv[4] = *(const floatx4*)&xi[row * D + c8 + 4];
  __syncthreads();

  const _Float16* src = t2 + (size_t)row * N * D;
  const float* xjb = xj + (size_t)b * N * D;
  float acc8[8] = {};
  #pragma unroll
  for (int u = 0; u < 8; ++u) {
    const int j = u * 16 + jr;           // j&15 == jr
    if (sMask[j] != 0.f) {
      const half8 tv = *(const half8*)(src + j * D + (((t & 15) ^ jr) << 3));
      const floatx4 xj0 = *(const floatx4*)&xjb[j * D + c8];
      const floatx4 xj1 = *(const floatx4*)&xjb[j * D + c8 + 4];
      #pragma unroll
      for (int r = 0; r < 4; ++r) {
        acc8[r]     += fmaxf(xiv[r] + xj0[r] + (float)tv[r], 0.f);
        acc8[4 + r] += fmaxf(xiv[4 + r] + xj1[r] + (float)tv[4 + r], 0.f);
      }
    }
  }
  #pragma unroll
  for (int k = 0; k < 8; ++k) hp[jr][t & 15][k] = acc8[k];
  __syncthreads();
  if (t < D) {
    float s = 0.f;
    #pragma unroll
    for (int g = 0; g < 16; ++g) s += hp[g][t >> 3][t & 7];
    rowsum[row * D + t] = s;
  }
}

// ---------------------------------------------------------------------------
// K7: head MLP. 16 blocks.
// ---------------------------------------------------------------------------
__global__ __launch_bounds__(128) void k_head(
    const float* __restrict__ rowsum,
    const float* __restrict__ w1, const float* __restrict__ b1,
    const float* __restrict__ w2, const float* __restrict__ b2,
    const float* __restrict__ w3, const float* __restrict__ b3,
    float* __restrict__ out) {
  const int b = blockIdx.x;
  const int c = threadIdx.x;
  __shared__ float hr[D], h1r[D], h2r[D];
  const float* rs = rowsum + (size_t)b * N * D;
  float s = 0.f;
  for (int i = 0; i < N; ++i) s += rs[i * D + c];
  hr[c] = s * (1.f / (N * N));
  __syncthreads();
  float a = b1[c];
  #pragma unroll 8
  for (int k = 0; k < D; ++k) a = fmaf(hr[k], w1[k * D + c], a);
  h1r[c] = fmaxf(a, 0.f);
  __syncthreads();
  a = b2[c];
  #pragma unroll 8
  for (int k = 0; k < D; ++k) a = fmaf(h1r[k], w2[k * D + c], a);
  h2r[c] = fmaxf(a, 0.f);
  __syncthreads();
  hr[c] = h2r[c] * w3[c];
  __syncthreads();
  if (c == 0) {
    float s2 = b3[0];
    for (int k = 0; k < D; ++k) s2 += hr[k];
    out[b] = s2;
  }
}

// ---------------------------------------------------------------------------
extern "C" void kernel_launch(void* const* d_in, const int* in_sizes, int n_in,
                              void* d_out, int out_size, void* d_ws, size_t ws_size,
                              hipStream_t stream) {
  const int*   ei  = (const int*)d_in[0];
  const float* x0  = (const float*)d_in[1];
  const float* ea  = (const float*)d_in[2];
  const float* wm0 = (const float*)d_in[3];
  const float* bm0 = (const float*)d_in[4];
  const float* wn0 = (const float*)d_in[5];
  const float* bn0 = (const float*)d_in[6];
  const float* wm1 = (const float*)d_in[7];
  const float* bm1 = (const float*)d_in[8];
  const float* wn1 = (const float*)d_in[9];
  const float* bn1 = (const float*)d_in[10];
  const float* wm2 = (const float*)d_in[11];
  const float* bm2 = (const float*)d_in[12];
  const float* wh1 = (const float*)d_in[15];
  const float* bh1 = (const float*)d_in[16];
  const float* wh2 = (const float*)d_in[17];
  const float* bh2 = (const float*)d_in[18];
  const float* wh3 = (const float*)d_in[19];
  const float* bh3 = (const float*)d_in[20];
  float* out = (float*)d_out;

  _Float16* msg0h = (_Float16*)d_ws;                 // [B,N,N,D] fp16: msg0 -> T2
  _Float16* weT1  = msg0h + (size_t)B * N * N * D;
  _Float16* weT2  = weT1 + D * D;
  float* f = (float*)(weT2 + D * D);
  size_t off = 0;
  const size_t R = (size_t)B * N * D;
  float* xi0  = f + off; off += R;
  float* xj0  = f + off; off += R;
  float* x1   = f + off; off += R;
  float* xi1  = f + off; off += R;
  float* xj1  = f + off; off += R;
  float* xi2  = f + off; off += R;
  float* xj2  = f + off; off += R;
  float* rsum = f + off; off += R;

  // agg scratch: rsum buffer is dead until k_fin, so it carries agg0
  // (k_edge0 -> k_node1) and then agg1 (k_mid -> k_node2). Stream order
  // guarantees each consumer reads before the next producer overwrites.
  float* aggS = rsum;

  const int rows = B * N;   // 2048
  k_pre  <<<512 + 128, 256, 0, stream>>>(x0, wm0, bm0, wm1, wm2,
                                         xi0, xj0, weT1, weT2);
  k_edge0<<<rows, 256, 0, stream>>>(ei, ea, wm0, xi0, xj0, msg0h, aggS);
  k_node1<<<rows / 4, 256, 0, stream>>>(x0, aggS, wn0, bn0, wm1, bm1,
                                        x1, xi1, xj1);
  k_mid  <<<rows / 2, 256, 0, stream>>>(ei, weT1, weT2, xi1, xj1, msg0h,
                                        aggS);
  k_node2<<<rows / 4, 256, 0, stream>>>(x1, aggS, wn1, bn1, wm2, bm2,
                                        xi2, xj2);
  k_fin  <<<rows, 256, 0, stream>>>(ei, msg0h, xi2, xj2, rsum);
  k_head <<<B,    128, 0, stream>>>(rsum, wh1, bh1, wh2, bh2, wh3, bh3, out);
}